// Round 10
// baseline (1920.822 us; speedup 1.0000x reference)
//
#include <hip/hip_runtime.h>
#include <hip/hip_bf16.h>
#include <math.h>

#define NB   4
#define NC   32
#define SVT  262144      // 64^3
#define VT   4096        // 64*64
#define NLAY 4
#define TWOPI_64 0.09817477042468103f

typedef __attribute__((ext_vector_type(8))) short bf16x8;
typedef __attribute__((ext_vector_type(4))) float f32x4;
typedef __attribute__((ext_vector_type(4))) unsigned short us4;

// tanh-form GELU via hw exp2/rcp; |err| vs exact erf-GELU < ~2.5e-4
__device__ __forceinline__ float gelu_f(float x){
    float x2 = x * x;
    float u  = x * __builtin_fmaf(-0.10294322f, x2, -2.30220795f);
    float e  = __builtin_amdgcn_exp2f(u);
    return x * __builtin_amdgcn_rcpf(1.0f + e);
}

__device__ __forceinline__ unsigned short f2bf(float f){
    union { __hip_bfloat16 h; unsigned short u; } cv;
    cv.h = __float2bfloat16(f);
    return cv.u;
}
__device__ __forceinline__ float bf2f(unsigned short u){
    return __uint_as_float(((unsigned int)u) << 16);
}

// 8-bf16 fragment from 8B-aligned LDS (two ds_read_b64)
__device__ __forceinline__ bf16x8 lds8(const unsigned short* p){
    us4 a = *(const us4*)p;
    us4 b = *(const us4*)(p + 4);
    bf16x8 r;
    r[0]=(short)a[0]; r[1]=(short)a[1]; r[2]=(short)a[2]; r[3]=(short)a[3];
    r[4]=(short)b[0]; r[5]=(short)b[1]; r[6]=(short)b[2]; r[7]=(short)b[3];
    return r;
}

// ------------- weight prep: bf16 transposes + twiddle tables + pb ---------
__global__ __launch_bounds__(256) void k_prep(
    const float* __restrict__ params,
    const float* __restrict__ s1w, const float* __restrict__ s1b,
    const float* __restrict__ s2w, const float* __restrict__ s3w,
    const float* __restrict__ conv_w,
    unsigned short* __restrict__ w2bf,   // [4][c 128][k 128]
    unsigned short* __restrict__ w3bf,   // [4][c2 32][k 128]
    unsigned short* __restrict__ tdft,   // [2(hi,lo)][32 o][64 t]
    unsigned short* __restrict__ T1h, unsigned short* __restrict__ T1l, // [128][64]
    unsigned short* __restrict__ T2h, unsigned short* __restrict__ T2l, // [64][32]
    float* __restrict__ pbq,             // [4 l][4 b][128]
    unsigned short* __restrict__ w1dup,  // [4 l][128][8]
    unsigned short* __restrict__ wcvh, unsigned short* __restrict__ wcvl) // [4][32 o][32 i]
{
    int g = blockIdx.x * 256 + threadIdx.x;
    if (g < 65536){
        int l = g >> 14, r = g & 16383;
        int c = r >> 7, k = r & 127;
        w2bf[g] = f2bf(s2w[l*16384 + k*128 + c]);
        return;
    }
    g -= 65536;
    if (g < 16384){
        int l = g >> 12, r = g & 4095;
        int c2 = r >> 7, k = r & 127;
        w3bf[g] = f2bf(s3w[l*4096 + k*32 + c2]);
        return;
    }
    g -= 16384;
    if (g < 2048){
        int o = g >> 6, t = g & 63;
        float val = 0.f;
        if (o < 24){
            int kz = o >> 1;
            float ang = (float)((kz * t) & 63) * TWOPI_64;
            float sn, cs; sincosf(ang, &sn, &cs);
            val = (o & 1) ? -sn : cs;      // forward DFT: e^{-i theta}
        }
        unsigned short h = f2bf(val);
        tdft[g]        = h;
        tdft[2048 + g] = f2bf(val - bf2f(h));
        return;
    }
    g -= 2048;
    if (g < 8192){           // T1 (unused by fused path; kept)
        int col = g >> 6, k1 = g & 63;
        int v = col >> 1, pout = col & 1;
        float val = 0.f;
        if (k1 < 48){
            int ky = k1 >> 1, pin = k1 & 1;
            int kya = (ky < 12) ? ky : ky + 40;
            float ang = (float)((kya * v) & 63) * TWOPI_64;
            float sn, cs; sincosf(ang, &sn, &cs);
            val = pout == 0 ? (pin == 0 ? cs : -sn) : (pin == 0 ? sn : cs);
        }
        unsigned short h = f2bf(val);
        T1h[g] = h;
        T1l[g] = f2bf(val - bf2f(h));
        return;
    }
    g -= 8192;
    if (g < 2048){           // T2: real inverse over kz -> t (norm + x2 folded)
        int t = g >> 5, k2 = g & 31;
        float val = 0.f;
        if (k2 < 24){
            int kz = k2 >> 1, part = k2 & 1;
            float wk = (kz == 0) ? 1.f : 2.f;
            float ang = (float)((kz * t) & 63) * TWOPI_64;
            float sn, cs; sincosf(ang, &sn, &cs);
            val = (part ? -sn : cs) * wk * (1.f / 262144.f);
        }
        unsigned short h = f2bf(val);
        T2h[g] = h;
        T2l[g] = f2bf(val - bf2f(h));
        return;
    }
    g -= 2048;
    if (g < 2048){           // pbq[l][b][h]
        int l = g >> 9, b = (g >> 7) & 3, h = g & 127;
        float acc = s1b[l*128 + h];
        #pragma unroll
        for (int j = 0; j < 6; ++j)
            acc += params[b*6 + j] * bf2f(f2bf(s1w[l*1152 + (3 + j)*128 + h]));
        pbq[g] = acc;
        return;
    }
    g -= 2048;
    if (g < 4096){           // w1dup[l][h][slot]: rows 0-2 dup in 0-2 & 4-6
        int l = g >> 10, rem = g & 1023;
        int h = rem >> 3, slot = rem & 7;
        float val = 0.f;
        if (slot != 3 && slot != 7){
            int row = (slot < 3) ? slot : slot - 4;
            val = bf2f(f2bf(s1w[l*1152 + row*128 + h]));
        }
        w1dup[g] = f2bf(val);
        return;
    }
    g -= 4096;
    if (g < 4096){           // conv weights hi/lo, [l][o][i]
        float val = conv_w[g];
        unsigned short h = f2bf(val);
        wcvh[g] = h;
        wcvl[g] = f2bf(val - bf2f(h));
    }
}

// ---------------- lift: x = z @ lift_w + lift_b, layout [B,C,S,V,T] -------
__global__ __launch_bounds__(256) void k_lift(
    const float* __restrict__ coords, const float* __restrict__ params,
    const float* __restrict__ lw, const float* __restrict__ lb,
    float* __restrict__ x)
{
    size_t g = (size_t)blockIdx.x * 256 + threadIdx.x;   // 0..1048575
    int b = (int)(g >> 18);
    size_t p = g & (size_t)(SVT - 1);
    float z[9];
    z[0] = coords[g*3+0]; z[1] = coords[g*3+1]; z[2] = coords[g*3+2];
    #pragma unroll
    for (int j = 0; j < 6; ++j) z[3+j] = params[b*6+j];
    #pragma unroll
    for (int c = 0; c < 32; ++c){
        float acc = lb[c];
        #pragma unroll
        for (int j = 0; j < 9; ++j) acc += z[j] * lw[j*32 + c];
        x[(size_t)(b*32 + c) * SVT + p] = acc;
    }
}

// ------- fused forward DFT t (MFMA split-bf16) then v: x -> X2[bc][kz][ky][s]
__global__ __launch_bounds__(256) void k_fwdTV(
    const float* __restrict__ x, const unsigned short* __restrict__ tdft,
    float2* __restrict__ X2)
{
    __shared__ __align__(16) unsigned short Ahi[64][72], Alo[64][72];
    __shared__ __align__(16) unsigned short Bhi[32][72], Blo[32][72];
    __shared__ float2 a2[12][66];
    __shared__ float2 wtab[64];
    int tid = threadIdx.x;
    int bc = blockIdx.x >> 6;
    int s  = blockIdx.x & 63;
    if (tid < 64){
        float sn, cs;
        sincosf((float)tid * TWOPI_64, &sn, &cs);
        wtab[tid] = make_float2(cs, sn);
    }
    for (int i = tid; i < 2048; i += 256){
        int o = i >> 6, t = i & 63;
        Bhi[o][t] = tdft[i];
        Blo[o][t] = tdft[2048 + i];
    }
    // stage x -> hi/lo bf16
    {
        int row = tid >> 2, c0 = (tid & 3) << 4;
        const float* src = x + (size_t)bc * SVT + (size_t)s * VT + row*64 + c0;
        #pragma unroll
        for (int q = 0; q < 4; ++q){
            float4 v4 = *(const float4*)&src[q*4];
            float vv[4] = {v4.x, v4.y, v4.z, v4.w};
            #pragma unroll
            for (int e = 0; e < 4; ++e){
                unsigned short h = f2bf(vv[e]);
                Ahi[row][c0 + q*4 + e] = h;
                Alo[row][c0 + q*4 + e] = f2bf(vv[e] - bf2f(h));
            }
        }
    }
    __syncthreads();
    // stage 1: wave w computes v-rows 16w..16w+15, 24 outputs (kz x re/im)
    int l = tid & 63, w = tid >> 6;
    int lr = l & 15, kg = l >> 4;
    int r0 = w << 4;
    f32x4 acc[2];
    acc[0] = (f32x4){0.f,0.f,0.f,0.f}; acc[1] = (f32x4){0.f,0.f,0.f,0.f};
    #pragma unroll
    for (int kc = 0; kc < 2; ++kc){
        int ko = kc*32 + kg*8;
        bf16x8 ah = *(const bf16x8*)&Ahi[r0 + lr][ko];
        bf16x8 al = *(const bf16x8*)&Alo[r0 + lr][ko];
        #pragma unroll
        for (int n = 0; n < 2; ++n){
            bf16x8 bh = *(const bf16x8*)&Bhi[n*16 + lr][ko];
            bf16x8 bl = *(const bf16x8*)&Blo[n*16 + lr][ko];
            acc[n] = __builtin_amdgcn_mfma_f32_16x16x32_bf16(ah, bh, acc[n], 0, 0, 0);
            acc[n] = __builtin_amdgcn_mfma_f32_16x16x32_bf16(ah, bl, acc[n], 0, 0, 0);
            acc[n] = __builtin_amdgcn_mfma_f32_16x16x32_bf16(al, bh, acc[n], 0, 0, 0);
        }
    }
    #pragma unroll
    for (int n = 0; n < 2; ++n){
        int o = n*16 + lr;
        if (o < 24){
            int kz = o >> 1;
            #pragma unroll
            for (int r = 0; r < 4; ++r){
                int v = r0 + kg*4 + r;
                if (o & 1) a2[kz][v].y = acc[n][r];
                else       a2[kz][v].x = acc[n][r];
            }
        }
    }
    __syncthreads();
    // stage 2: DFT over v -> X2[bc][kz][ky][s]
    for (int task = tid; task < 288; task += 256){
        int kz = task % 12;
        int ky = task / 12;
        int kya = (ky < 12) ? ky : ky + 40;
        float re = 0.f, im = 0.f;
        for (int v = 0; v < 64; ++v){
            float2 wv = wtab[(kya * v) & 63];
            float2 a  = a2[kz][v];
            re += a.x * wv.x + a.y * wv.y;
            im += a.y * wv.x - a.x * wv.y;
        }
        X2[((size_t)(bc*12 + kz) * 24 + ky) * 64 + s] = make_float2(re, im);
    }
}

// ---------------- forward DFT over s: X2[bc][kz][ky][s] -> X3[bc][kx][ky][kz]
__global__ __launch_bounds__(256) void k_fwdS(
    const float2* __restrict__ X2, float2* __restrict__ X3)
{
    __shared__ float2 cin[32][65];
    __shared__ float2 wtab[64];
    int tid = threadIdx.x;
    if (tid < 64){
        float sn, cs; sincosf((float)tid * TWOPI_64, &sn, &cs);
        wtab[tid] = make_float2(cs, sn);
    }
    int rbase = blockIdx.x * 32;   // rows (bc,kz,ky), 36864 total
    for (int i = tid; i < 2048; i += 256){
        int row = i >> 6, s = i & 63;
        cin[row][s] = X2[(size_t)(rbase + row) * 64 + s];
    }
    __syncthreads();
    int row = tid & 31;
    int r = rbase + row;
    int kxg = tid >> 5;       // 0..7 -> 3 kx each
    int kxs[3];
    #pragma unroll
    for (int j = 0; j < 3; ++j){ int kxi = kxg*3 + j; kxs[j] = (kxi < 12) ? kxi : kxi + 40; }
    float re[3] = {0,0,0}, im[3] = {0,0,0};
    for (int s = 0; s < 64; ++s){
        float2 cv = cin[row][s];
        #pragma unroll
        for (int j = 0; j < 3; ++j){
            float2 wv = wtab[(kxs[j] * s) & 63];
            re[j] += cv.x * wv.x + cv.y * wv.y;
            im[j] += cv.y * wv.x - cv.x * wv.y;
        }
    }
    int bc = r / 288; int kz = (r / 24) % 12; int ky = r % 24;
    #pragma unroll
    for (int j = 0; j < 3; ++j){
        int kxi = kxg*3 + j;
        X3[(size_t)bc * 6912 + (size_t)kxi * 288 + ky * 12 + kz] = make_float2(re[j], im[j]);
    }
}

// --------- per-mode channel mixing: coalesced W, X3 in regs, 4 o per block -
__global__ __launch_bounds__(256) void k_modemix(
    const float2* __restrict__ X3,
    const float* __restrict__ w1, const float* __restrict__ w2,
    const float* __restrict__ w3, const float* __restrict__ w4,
    int layer, float2* __restrict__ Y)
{
    __shared__ float2 wlds[32][64];   // [i][m], 16 KB
    int tid = threadIdx.x;
    int m   = tid & 63;
    int b   = tid >> 6;
    int corner = blockIdx.y >> 3;
    int o0     = (blockIdx.y & 7) * 4;
    int moff0  = blockIdx.x * 64;
    const float* wsrc = (corner==0 ? w1 : corner==1 ? w2 : corner==2 ? w3 : w4)
                        + (size_t)layer * 3538944;   // 32*32*1728*2
    int moff = moff0 + m;
    int m1  = moff / 144;
    int rem = moff - m1 * 144;
    int kx  = m1 + ((corner == 1 || corner == 3) ? 12 : 0);
    int mode_g = kx * 288 + rem + ((corner >= 2) ? 144 : 0);

    float xr[32], xi[32];
    const float2* xp = X3 + (size_t)b * 32 * 6912 + mode_g;
    #pragma unroll
    for (int i = 0; i < 32; ++i){
        float2 a = xp[(size_t)i * 6912];
        xr[i] = a.x; xi[i] = a.y;
    }
    for (int oo = 0; oo < 4; ++oo){
        int o = o0 + oo;
        __syncthreads();
        for (int j = tid; j < 2048; j += 256){
            int i = j >> 6, mm = j & 63;
            wlds[i][mm] = *(const float2*)&wsrc[((size_t)(i*32 + o) * 1728 + moff0 + mm) * 2];
        }
        __syncthreads();
        float re = 0.f, im = 0.f;
        #pragma unroll
        for (int i = 0; i < 32; ++i){
            float2 wv = wlds[i][m];
            re += xr[i]*wv.x - xi[i]*wv.y;
            im += xr[i]*wv.y + xi[i]*wv.x;
        }
        Y[(size_t)(b*32 + o) * 6912 + mode_g] = make_float2(re, im);
    }
}

// ---------------- inverse over s: Y[bo][kx][ky][kz] -> Z1[bo][kz][s][ky] ---
__global__ __launch_bounds__(256) void k_invS(
    const float2* __restrict__ Y, float2* __restrict__ Z1)
{
    __shared__ float2 yin[24][24];
    __shared__ float2 wtab[64];
    int tid = threadIdx.x;
    if (tid < 64){
        float sn, cs; sincosf((float)tid * TWOPI_64, &sn, &cs);
        wtab[tid] = make_float2(cs, sn);
    }
    int bo = blockIdx.x / 12;
    int kz = blockIdx.x % 12;
    for (int i = tid; i < 576; i += 256){
        int kx = i / 24, ky = i % 24;
        yin[kx][ky] = Y[(size_t)bo * 6912 + (size_t)kx * 288 + ky * 12 + kz];
    }
    __syncthreads();
    int s = tid & 63;
    int kyg = tid >> 6;   // 0..3 -> 6 ky each
    float re[6] = {0,0,0,0,0,0}, im[6] = {0,0,0,0,0,0};
    for (int kxi = 0; kxi < 24; ++kxi){
        int kxa = (kxi < 12) ? kxi : kxi + 40;
        float2 wv = wtab[(kxa * s) & 63];     // e^{+i theta}
        #pragma unroll
        for (int j = 0; j < 6; ++j){
            float2 a = yin[kxi][kyg*6 + j];
            re[j] += a.x * wv.x - a.y * wv.y;
            im[j] += a.x * wv.y + a.y * wv.x;
        }
    }
    #pragma unroll
    for (int j = 0; j < 6; ++j){
        int ky = kyg*6 + j;
        Z1[((size_t)(bo*12 + kz) * 64 + s) * 24 + ky] = make_float2(re[j], im[j]);
    }
}

// ===== fused layer tail: conv + inv-v + inv-t + gelu + skip MLP (+proj) ====
// block = (b, s, v-pair): 128 points x 32 channels; 256 thr = 4 waves.
// LDS union (52,736 B): wtab | XTh/XTl (xf overlay) | A2h/A2l (A1 overlay;
// outsT/hs/p1wS/smB overlay A1 after phase D).
template<int LAST>
__global__ __launch_bounds__(256, 4) void k_fused(
    const float* __restrict__ xin, const float2* __restrict__ Z1,
    const unsigned short* __restrict__ T2h, const unsigned short* __restrict__ T2l,
    const unsigned short* __restrict__ wcvh, const unsigned short* __restrict__ wcvl,
    const float* __restrict__ cb, const float* __restrict__ coords,
    const unsigned short* __restrict__ w1dup, const float* __restrict__ pbq,
    const unsigned short* __restrict__ w2bf, const float* __restrict__ s2b,
    const unsigned short* __restrict__ w3bf, const float* __restrict__ s3b,
    int layer, float* __restrict__ xout,
    const float* __restrict__ p1w, const float* __restrict__ p1b,
    const float* __restrict__ p2w, const float* __restrict__ p2b,
    float* __restrict__ out)
{
    __shared__ __align__(16) char LB[52736];
    float2* wtab = (float2*)&LB[0];                                     // [64]
    unsigned short (*XTh)[36] = (unsigned short(*)[36])&LB[512];        // [128][36]
    unsigned short (*XTl)[36] = (unsigned short(*)[36])&LB[9728];       // [128][36]
    float* xf = (float*)&LB[512];                                       // [32][132] overlay
    unsigned short (*A2h)[36] = (unsigned short(*)[36])&LB[18944];      // [64][36]
    unsigned short (*A2l)[36] = (unsigned short(*)[36])&LB[23552];      // [64][36]
    unsigned short (*A1)[132] = (unsigned short(*)[132])&LB[18944];     // [128][132] overlay
    float* outsT = (float*)&LB[18944];                                  // [32][132] overlay
    float* hs    = (float*)&LB[35840];                                  // [128][17]
    float* p1wS  = (float*)&LB[44544];                                  // [512]
    float* smB   = (float*)&LB[46592];                                  // [33]

    int tid = threadIdx.x;
    int vp = blockIdx.x & 31;
    int s  = (blockIdx.x >> 5) & 63;
    int b  = blockIdx.x >> 11;
    size_t base    = (size_t)b*32*SVT + (size_t)s*VT + (size_t)vp*128;  // chan-0
    size_t gptbase = (size_t)b*SVT    + (size_t)s*VT + (size_t)vp*128;  // point idx

    const unsigned short* w2g = w2bf + (size_t)layer * 16384;
    const unsigned short* w3g = w3bf + (size_t)layer * 4096;
    const unsigned short* w1g = w1dup + (size_t)layer * 1024;
    const float* pbg = pbq + layer*512 + b*128;
    const float* b2g = s2b + layer*128;

    if (tid < 64){
        float sn, cs; sincosf((float)tid * TWOPI_64, &sn, &cs);
        wtab[tid] = make_float2(cs, sn);
    }
    // phase 0: stage x -> XT hi/lo (thread = pt x chan-half)
    {
        int pt = tid & 127, half = tid >> 7;
        const float* xp = xin + base + pt;
        #pragma unroll
        for (int q = 0; q < 2; ++q){
            int o0 = half*16 + q*8;
            us4 pa, pb_, la, lb_;
            #pragma unroll
            for (int e = 0; e < 4; ++e){
                float v = xp[(size_t)(o0 + e) * SVT];
                unsigned short h = f2bf(v);
                pa[e] = h; la[e] = f2bf(v - bf2f(h));
            }
            #pragma unroll
            for (int e = 0; e < 4; ++e){
                float v = xp[(size_t)(o0 + 4 + e) * SVT];
                unsigned short h = f2bf(v);
                pb_[e] = h; lb_[e] = f2bf(v - bf2f(h));
            }
            *(us4*)&XTh[pt][o0]     = pa;
            *(us4*)&XTh[pt][o0 + 4] = pb_;
            *(us4*)&XTl[pt][o0]     = la;
            *(us4*)&XTl[pt][o0 + 4] = lb_;
        }
    }
    __syncthreads();                       // B0: wtab + XT visible
    // zero A2 pad cols 24..31 (128 (row,g4) pairs x {h,l})
    {
        us4 z4 = (us4){0,0,0,0};
        int t2 = tid & 127;
        int row = t2 >> 1, g4 = t2 & 1;
        if (tid < 128) *(us4*)&A2h[row][24 + g4*4] = z4;
        else           *(us4*)&A2l[row][24 + g4*4] = z4;
    }
    // phase 1: inverse DFT over ky (fp32) -> A2[vloc*32+o][2kz+part] hi/lo
    #pragma unroll
    for (int j = 0; j < 3; ++j){
        int task = tid + j*256;            // 768 = 64 rows x 12 kz
        int row = task / 12, kz = task - row*12;
        int vloc = row >> 5, o = row & 31;
        int v = vp*2 + vloc;
        const float2* zp = Z1 + ((size_t)((b*32 + o)*12 + kz) * 64 + s) * 24;
        float re = 0.f, im = 0.f;
        #pragma unroll
        for (int ky = 0; ky < 24; ++ky){
            int kya = (ky < 12) ? ky : ky + 40;
            float2 wv = wtab[(kya * v) & 63];
            float2 a = zp[ky];
            re += a.x * wv.x - a.y * wv.y;
            im += a.x * wv.y + a.y * wv.x;
        }
        unsigned short hr = f2bf(re), hm = f2bf(im);
        A2h[row][2*kz  ] = hr; A2l[row][2*kz  ] = f2bf(re - bf2f(hr));
        A2h[row][2*kz+1] = hm; A2l[row][2*kz+1] = f2bf(im - bf2f(hm));
    }
    __syncthreads();                       // B0b: A2 ready

    int l = tid & 63, w = tid >> 6, lr = l & 15, kg = l >> 4;
    int otile = w & 1, vloc_w = w >> 1;

    // phase 2: conv MFMA -> dcv[ptt] (o = otile*16+kg*4+r, t = ptt*16+lr)
    f32x4 dcv[4], dt[4];
    {
        const unsigned short* wh = wcvh + layer*1024 + (otile*16 + lr)*32 + kg*8;
        const unsigned short* wl = wcvl + layer*1024 + (otile*16 + lr)*32 + kg*8;
        bf16x8 ah = *(const bf16x8*)wh;
        bf16x8 al = *(const bf16x8*)wl;
        #pragma unroll
        for (int ptt = 0; ptt < 4; ++ptt){
            int ptr_ = vloc_w*64 + ptt*16 + lr;
            bf16x8 bh = lds8(&XTh[ptr_][kg*8]);
            bf16x8 bl = lds8(&XTl[ptr_][kg*8]);
            f32x4 d = (f32x4){0.f,0.f,0.f,0.f};
            d = __builtin_amdgcn_mfma_f32_16x16x32_bf16(ah, bh, d, 0, 0, 0);
            d = __builtin_amdgcn_mfma_f32_16x16x32_bf16(ah, bl, d, 0, 0, 0);
            d = __builtin_amdgcn_mfma_f32_16x16x32_bf16(al, bh, d, 0, 0, 0);
            dcv[ptt] = d;
        }
    }
    // phase 3: inverse-t MFMA -> dt[ptt] (row = w*16+kg*4+r matches dcv's o)
    {
        bf16x8 ah = lds8(&A2h[w*16 + lr][kg*8]);
        bf16x8 al = lds8(&A2l[w*16 + lr][kg*8]);
        #pragma unroll
        for (int ptt = 0; ptt < 4; ++ptt){
            bf16x8 bh = *(const bf16x8*)&T2h[(ptt*16 + lr)*32 + kg*8];
            bf16x8 bl = *(const bf16x8*)&T2l[(ptt*16 + lr)*32 + kg*8];
            f32x4 d = (f32x4){0.f,0.f,0.f,0.f};
            d = __builtin_amdgcn_mfma_f32_16x16x32_bf16(ah, bh, d, 0, 0, 0);
            d = __builtin_amdgcn_mfma_f32_16x16x32_bf16(ah, bl, d, 0, 0, 0);
            d = __builtin_amdgcn_mfma_f32_16x16x32_bf16(al, bh, d, 0, 0, 0);
            dt[ptt] = d;
        }
    }
    __syncthreads();                       // B1: XT & A2 reads complete

    // combine in-register: xf = gelu(x1 + x2 + cb)  -> LDS (overlays XT)
    {
        float4 cbv = *(const float4*)&cb[layer*32 + otile*16 + kg*4];
        float cbs[4] = {cbv.x, cbv.y, cbv.z, cbv.w};
        #pragma unroll
        for (int ptt = 0; ptt < 4; ++ptt){
            int pt = vloc_w*64 + ptt*16 + lr;
            #pragma unroll
            for (int r = 0; r < 4; ++r){
                int o = otile*16 + kg*4 + r;
                xf[o*132 + pt] = gelu_f(dt[ptt][r] + dcv[ptt][r] + cbs[r]);
            }
        }
    }
    // phase B: h1 = gelu(z@w1 + pb) -> A1 (overlays A2 region)
    #pragma unroll
    for (int q = 0; q < 2; ++q){
        bf16x8 bz = (bf16x8){0,0,0,0,0,0,0,0};
        if (kg == 0){
            size_t gp = gptbase + (size_t)w*32 + q*16 + lr;
            float z0 = coords[gp*3+0], z1 = coords[gp*3+1], z2 = coords[gp*3+2];
            unsigned short h0 = f2bf(z0), h1 = f2bf(z1), h2 = f2bf(z2);
            bz[0] = (short)h0; bz[1] = (short)h1; bz[2] = (short)h2;
            bz[4] = (short)f2bf(z0 - bf2f(h0));
            bz[5] = (short)f2bf(z1 - bf2f(h1));
            bz[6] = (short)f2bf(z2 - bf2f(h2));
        }
        f32x4 accB[8];
        #pragma unroll
        for (int m = 0; m < 8; ++m) accB[m] = (f32x4){0.f,0.f,0.f,0.f};
        #pragma unroll
        for (int m = 0; m < 8; ++m){
            bf16x8 af = *(const bf16x8*)&w1g[(m*16 + lr)*8];
            accB[m] = __builtin_amdgcn_mfma_f32_16x16x32_bf16(af, bz, accB[m], 0, 0, 0);
        }
        #pragma unroll
        for (int m = 0; m < 8; ++m){
            int c0 = m*16 + kg*4;
            float4 bb = *(const float4*)&pbg[c0];
            us4 pk4;
            pk4[0] = f2bf(gelu_f(accB[m][0] + bb.x));
            pk4[1] = f2bf(gelu_f(accB[m][1] + bb.y));
            pk4[2] = f2bf(gelu_f(accB[m][2] + bb.z));
            pk4[3] = f2bf(gelu_f(accB[m][3] + bb.w));
            *(us4*)&A1[w*32 + q*16 + lr][c0] = pk4;
        }
    }
    __syncthreads();                       // B2: h1 + xf visible

    // phase C: h2pre = h1 @ w2 (swapped -> D[c][pt]); wave: c-tiles {2w,2w+1}
    f32x4 accC[2][8];
    #pragma unroll
    for (int mi = 0; mi < 2; ++mi)
        #pragma unroll
        for (int ptt = 0; ptt < 8; ++ptt) accC[mi][ptt] = (f32x4){0.f,0.f,0.f,0.f};
    #pragma unroll
    for (int kc = 0; kc < 4; ++kc){
        int ko = kc*32 + kg*8;
        bf16x8 a0 = *(const bf16x8*)&w2g[((2*w    )*16 + lr)*128 + ko];
        bf16x8 a1 = *(const bf16x8*)&w2g[((2*w + 1)*16 + lr)*128 + ko];
        #pragma unroll
        for (int ptt = 0; ptt < 8; ++ptt){
            bf16x8 bb = lds8(&A1[ptt*16 + lr][ko]);
            accC[0][ptt] = __builtin_amdgcn_mfma_f32_16x16x32_bf16(a0, bb, accC[0][ptt], 0, 0, 0);
            accC[1][ptt] = __builtin_amdgcn_mfma_f32_16x16x32_bf16(a1, bb, accC[1][ptt], 0, 0, 0);
        }
    }
    __syncthreads();                       // B3: all h1 reads done
    #pragma unroll
    for (int mi = 0; mi < 2; ++mi)
        #pragma unroll
        for (int ptt = 0; ptt < 8; ++ptt){
            int c0 = (2*w + mi)*16 + kg*4;
            float4 bb = *(const float4*)&b2g[c0];
            us4 pk4;
            pk4[0] = f2bf(gelu_f(accC[mi][ptt][0] + bb.x));
            pk4[1] = f2bf(gelu_f(accC[mi][ptt][1] + bb.y));
            pk4[2] = f2bf(gelu_f(accC[mi][ptt][2] + bb.z));
            pk4[3] = f2bf(gelu_f(accC[mi][ptt][3] + bb.w));
            *(us4*)&A1[ptt*16 + lr][c0] = pk4;
        }
    __syncthreads();                       // B4: h2 visible

    // phase D: skip-out = h2 @ w3 (D[pt][c2]); wave: n-tile w&1, pt-tiles 4
    int nD  = w & 1;
    int pt0 = (w >> 1) * 4;
    float b3v = s3b[layer*32 + nD*16 + lr];
    f32x4 c3[4];
    #pragma unroll
    for (int q = 0; q < 4; ++q) c3[q] = (f32x4){0.f,0.f,0.f,0.f};
    #pragma unroll
    for (int kc = 0; kc < 4; ++kc){
        int ko = kc*32 + kg*8;
        bf16x8 bw3 = *(const bf16x8*)&w3g[(nD*16 + lr)*128 + ko];
        #pragma unroll
        for (int q = 0; q < 4; ++q){
            bf16x8 aa = lds8(&A1[(pt0 + q)*16 + lr][ko]);
            c3[q] = __builtin_amdgcn_mfma_f32_16x16x32_bf16(aa, bw3, c3[q], 0, 0, 0);
        }
    }
    __syncthreads();                       // B5: A1 reads done -> overlay outsT
    {
        int c2 = nD*16 + lr;
        #pragma unroll
        for (int q = 0; q < 4; ++q){
            int p0 = (pt0 + q)*16 + kg*4;
            float4 v4;
            v4.x = c3[q][0] + b3v; v4.y = c3[q][1] + b3v;
            v4.z = c3[q][2] + b3v; v4.w = c3[q][3] + b3v;
            *(float4*)&outsT[c2*132 + p0] = v4;
        }
    }
    if (LAST){
        for (int i = tid; i < 512; i += 256) p1wS[i] = p1w[i];
        if (tid < 16){ smB[tid] = p1b[tid]; smB[16 + tid] = p2w[tid]; }
        if (tid == 32) smB[32] = p2b[0];
    }
    __syncthreads();                       // B6: outsT + xf ready

    // rmw: x_new = xf + skip -> global (or keep in LDS for LAST)
    {
        int c  = tid >> 3;        // 0..31
        int pg = tid & 7;         // 16 pts each
        float* xfp = &xf[c*132 + pg*16];
        float* otp = &outsT[c*132 + pg*16];
        float* gp  = xout + base + (size_t)c*SVT + (size_t)pg*16;
        #pragma unroll
        for (int i = 0; i < 16; i += 4){
            float4 sv = *(const float4*)&otp[i];
            float4 xv = *(const float4*)&xfp[i];
            sv.x += xv.x; sv.y += xv.y; sv.z += xv.z; sv.w += xv.w;
            if (LAST) *(float4*)&otp[i] = sv;
            else      *(float4*)&gp[i]  = sv;
        }
    }
    if (LAST){
        __syncthreads();
        {
            int p  = tid & 127;
            int jq = tid >> 7;    // 2 halves x 8 j
            float h[8];
            #pragma unroll
            for (int j = 0; j < 8; ++j) h[j] = smB[jq*8 + j];
            for (int c = 0; c < 32; ++c){
                float xv = outsT[c*132 + p];
                #pragma unroll
                for (int j = 0; j < 8; ++j) h[j] += xv * p1wS[c*16 + jq*8 + j];
            }
            #pragma unroll
            for (int j = 0; j < 8; ++j) hs[p*17 + jq*8 + j] = h[j];
        }
        __syncthreads();
        if (tid < 128){
            float acc = smB[32];
            #pragma unroll
            for (int j = 0; j < 16; ++j) acc += gelu_f(hs[tid*17 + j]) * smB[16 + j];
            out[gptbase + tid] = acc;
        }
    }
}

extern "C" void kernel_launch(void* const* d_in, const int* in_sizes, int n_in,
                              void* d_out, int out_size, void* d_ws, size_t ws_size,
                              hipStream_t stream)
{
    (void)in_sizes; (void)n_in; (void)out_size; (void)ws_size;
    const float* coords = (const float*)d_in[0];
    const float* params = (const float*)d_in[1];
    const float* lift_w = (const float*)d_in[2];
    const float* lift_b = (const float*)d_in[3];
    const float* sw1    = (const float*)d_in[4];
    const float* sw2    = (const float*)d_in[5];
    const float* sw3    = (const float*)d_in[6];
    const float* sw4    = (const float*)d_in[7];
    const float* conv_w = (const float*)d_in[8];
    const float* conv_b = (const float*)d_in[9];
    const float* s1w    = (const float*)d_in[10];
    const float* s1b    = (const float*)d_in[11];
    const float* s2w    = (const float*)d_in[12];
    const float* s2b    = (const float*)d_in[13];
    const float* s3w    = (const float*)d_in[14];
    const float* s3b    = (const float*)d_in[15];
    const float* p1w    = (const float*)d_in[16];
    const float* p1b    = (const float*)d_in[17];
    const float* p2w    = (const float*)d_in[18];
    const float* p2b    = (const float*)d_in[19];
    float* out = (float*)d_out;

    char* ws = (char*)d_ws;
    float*  xA = (float*)(ws);                                    // 134,217,728
    float2* X2 = (float2*)(ws + 134217728ull);                    //  18,874,368 (also Z1)
    float2* X3 = (float2*)(ws + 153092096ull);                    //   7,077,888
    float2* Yb = (float2*)(ws + 160169984ull);                    //   7,077,888
    unsigned short* w2bf  = (unsigned short*)(ws + 167247872ull); //     131,072
    unsigned short* w3bf  = (unsigned short*)(ws + 167378944ull); //      32,768
    unsigned short* tdft  = (unsigned short*)(ws + 167411712ull); //       8,192
    unsigned short* T1h   = (unsigned short*)(ws + 167419904ull); //      16,384
    unsigned short* T1l   = (unsigned short*)(ws + 167436288ull); //      16,384
    unsigned short* T2h   = (unsigned short*)(ws + 167452672ull); //       4,096
    unsigned short* T2l   = (unsigned short*)(ws + 167456768ull); //       4,096
    float*          pbq   = (float*)(ws + 167460864ull);          //       8,192
    unsigned short* w1dup = (unsigned short*)(ws + 167469056ull); //       8,192
    unsigned short* wcvh  = (unsigned short*)(ws + 167477248ull); //       8,192
    unsigned short* wcvl  = (unsigned short*)(ws + 167485440ull); //       8,192
    // total 167,493,632 B

    k_prep<<<408, 256, 0, stream>>>(params, s1w, s1b, s2w, s3w, conv_w,
                                    w2bf, w3bf, tdft, T1h, T1l, T2h, T2l,
                                    pbq, w1dup, wcvh, wcvl);
    k_lift<<<4096, 256, 0, stream>>>(coords, params, lift_w, lift_b, xA);

    for (int l = 0; l < NLAY; ++l){
        k_fwdTV<<<8192, 256, 0, stream>>>(xA, tdft, X2);
        k_fwdS<<<1152, 256, 0, stream>>>(X2, X3);
        dim3 gmm(27, 32);
        k_modemix<<<gmm, 256, 0, stream>>>(X3, sw1, sw2, sw3, sw4, l, Yb);
        k_invS<<<1536, 256, 0, stream>>>(Yb, X2);          // Z1 overlays X2
        if (l < NLAY - 1)
            k_fused<0><<<8192, 256, 0, stream>>>(xA, X2, T2h, T2l, wcvh, wcvl,
                conv_b, coords, w1dup, pbq, w2bf, s2b, w3bf, s3b, l, xA,
                p1w, p1b, p2w, p2b, out);
        else
            k_fused<1><<<8192, 256, 0, stream>>>(xA, X2, T2h, T2l, wcvh, wcvl,
                conv_b, coords, w1dup, pbq, w2bf, s2b, w3bf, s3b, l, xA,
                p1w, p1b, p2w, p2b, out);
    }
}

// Round 11
// 1553.069 us; speedup vs baseline: 1.2368x; 1.2368x over previous
//
#include <hip/hip_runtime.h>
#include <hip/hip_bf16.h>
#include <math.h>

#define NB   4
#define NC   32
#define SVT  262144      // 64^3
#define VT   4096        // 64*64
#define NLAY 4
#define TWOPI_64 0.09817477042468103f

typedef __attribute__((ext_vector_type(8))) short bf16x8;
typedef __attribute__((ext_vector_type(4))) float f32x4;
typedef __attribute__((ext_vector_type(4))) unsigned short us4;

// tanh-form GELU via hw exp2/rcp; |err| vs exact erf-GELU < ~2.5e-4
__device__ __forceinline__ float gelu_f(float x){
    float x2 = x * x;
    float u  = x * __builtin_fmaf(-0.10294322f, x2, -2.30220795f);
    float e  = __builtin_amdgcn_exp2f(u);
    return x * __builtin_amdgcn_rcpf(1.0f + e);
}

__device__ __forceinline__ unsigned short f2bf(float f){
    union { __hip_bfloat16 h; unsigned short u; } cv;
    cv.h = __float2bfloat16(f);
    return cv.u;
}
__device__ __forceinline__ float bf2f(unsigned short u){
    return __uint_as_float(((unsigned int)u) << 16);
}

// ------------- weight prep: bf16 transposes + twiddle tables + pb ---------
__global__ __launch_bounds__(256) void k_prep(
    const float* __restrict__ params,
    const float* __restrict__ s1w, const float* __restrict__ s1b,
    const float* __restrict__ s2w, const float* __restrict__ s3w,
    const float* __restrict__ conv_w,
    unsigned short* __restrict__ w2bf,   // [4][c 128][k 128]
    unsigned short* __restrict__ w3bf,   // [4][c2 32][k 128]
    unsigned short* __restrict__ tdft,   // [2(hi,lo)][32 o][64 t]
    unsigned short* __restrict__ T1h, unsigned short* __restrict__ T1l, // [128][64]
    unsigned short* __restrict__ T2h, unsigned short* __restrict__ T2l, // [64][32]
    float* __restrict__ pbq,             // [4 l][4 b][128]
    unsigned short* __restrict__ w1dup,  // [4 l][128][8]
    unsigned short* __restrict__ wcvh, unsigned short* __restrict__ wcvl) // [4][32 o][32 i]
{
    int g = blockIdx.x * 256 + threadIdx.x;
    if (g < 65536){
        int l = g >> 14, r = g & 16383;
        int c = r >> 7, k = r & 127;
        w2bf[g] = f2bf(s2w[l*16384 + k*128 + c]);
        return;
    }
    g -= 65536;
    if (g < 16384){
        int l = g >> 12, r = g & 4095;
        int c2 = r >> 7, k = r & 127;
        w3bf[g] = f2bf(s3w[l*4096 + k*32 + c2]);
        return;
    }
    g -= 16384;
    if (g < 2048){
        int o = g >> 6, t = g & 63;
        float val = 0.f;
        if (o < 24){
            int kz = o >> 1;
            float ang = (float)((kz * t) & 63) * TWOPI_64;
            float sn, cs; sincosf(ang, &sn, &cs);
            val = (o & 1) ? -sn : cs;      // forward DFT: e^{-i theta}
        }
        unsigned short h = f2bf(val);
        tdft[g]        = h;
        tdft[2048 + g] = f2bf(val - bf2f(h));
        return;
    }
    g -= 2048;
    if (g < 8192){           // T1 (unused; kept for layout stability)
        int col = g >> 6, k1 = g & 63;
        int v = col >> 1, pout = col & 1;
        float val = 0.f;
        if (k1 < 48){
            int ky = k1 >> 1, pin = k1 & 1;
            int kya = (ky < 12) ? ky : ky + 40;
            float ang = (float)((kya * v) & 63) * TWOPI_64;
            float sn, cs; sincosf(ang, &sn, &cs);
            val = pout == 0 ? (pin == 0 ? cs : -sn) : (pin == 0 ? sn : cs);
        }
        unsigned short h = f2bf(val);
        T1h[g] = h;
        T1l[g] = f2bf(val - bf2f(h));
        return;
    }
    g -= 8192;
    if (g < 2048){           // T2: real inverse over kz -> t (norm + x2 folded)
        int t = g >> 5, k2 = g & 31;
        float val = 0.f;
        if (k2 < 24){
            int kz = k2 >> 1, part = k2 & 1;
            float wk = (kz == 0) ? 1.f : 2.f;
            float ang = (float)((kz * t) & 63) * TWOPI_64;
            float sn, cs; sincosf(ang, &sn, &cs);
            val = (part ? -sn : cs) * wk * (1.f / 262144.f);
        }
        unsigned short h = f2bf(val);
        T2h[g] = h;
        T2l[g] = f2bf(val - bf2f(h));
        return;
    }
    g -= 2048;
    if (g < 2048){           // pbq[l][b][h]
        int l = g >> 9, b = (g >> 7) & 3, h = g & 127;
        float acc = s1b[l*128 + h];
        #pragma unroll
        for (int j = 0; j < 6; ++j)
            acc += params[b*6 + j] * bf2f(f2bf(s1w[l*1152 + (3 + j)*128 + h]));
        pbq[g] = acc;
        return;
    }
    g -= 2048;
    if (g < 4096){           // w1dup[l][h][slot]: rows 0-2 dup in 0-2 & 4-6
        int l = g >> 10, rem = g & 1023;
        int h = rem >> 3, slot = rem & 7;
        float val = 0.f;
        if (slot != 3 && slot != 7){
            int row = (slot < 3) ? slot : slot - 4;
            val = bf2f(f2bf(s1w[l*1152 + row*128 + h]));
        }
        w1dup[g] = f2bf(val);
        return;
    }
    g -= 4096;
    if (g < 4096){           // conv weights hi/lo, [l][o][i]
        float val = conv_w[g];
        unsigned short h = f2bf(val);
        wcvh[g] = h;
        wcvl[g] = f2bf(val - bf2f(h));
    }
}

// ---------------- lift: x = z @ lift_w + lift_b, layout [B,C,S,V,T] -------
__global__ __launch_bounds__(256) void k_lift(
    const float* __restrict__ coords, const float* __restrict__ params,
    const float* __restrict__ lw, const float* __restrict__ lb,
    float* __restrict__ x)
{
    size_t g = (size_t)blockIdx.x * 256 + threadIdx.x;   // 0..1048575
    int b = (int)(g >> 18);
    size_t p = g & (size_t)(SVT - 1);
    float z[9];
    z[0] = coords[g*3+0]; z[1] = coords[g*3+1]; z[2] = coords[g*3+2];
    #pragma unroll
    for (int j = 0; j < 6; ++j) z[3+j] = params[b*6+j];
    #pragma unroll
    for (int c = 0; c < 32; ++c){
        float acc = lb[c];
        #pragma unroll
        for (int j = 0; j < 9; ++j) acc += z[j] * lw[j*32 + c];
        x[(size_t)(b*32 + c) * SVT + p] = acc;
    }
}

// ------- fused forward DFT t (MFMA split-bf16) then v: x -> X2[bc][kz][ky][s]
__global__ __launch_bounds__(256) void k_fwdTV(
    const float* __restrict__ x, const unsigned short* __restrict__ tdft,
    float2* __restrict__ X2)
{
    __shared__ __align__(16) unsigned short Ahi[64][72], Alo[64][72];
    __shared__ __align__(16) unsigned short Bhi[32][72], Blo[32][72];
    __shared__ float2 a2[12][66];
    __shared__ float2 wtab[64];
    int tid = threadIdx.x;
    int bc = blockIdx.x >> 6;
    int s  = blockIdx.x & 63;
    if (tid < 64){
        float sn, cs;
        sincosf((float)tid * TWOPI_64, &sn, &cs);
        wtab[tid] = make_float2(cs, sn);
    }
    for (int i = tid; i < 2048; i += 256){
        int o = i >> 6, t = i & 63;
        Bhi[o][t] = tdft[i];
        Blo[o][t] = tdft[2048 + i];
    }
    // stage x -> hi/lo bf16
    {
        int row = tid >> 2, c0 = (tid & 3) << 4;
        const float* src = x + (size_t)bc * SVT + (size_t)s * VT + row*64 + c0;
        #pragma unroll
        for (int q = 0; q < 4; ++q){
            float4 v4 = *(const float4*)&src[q*4];
            float vv[4] = {v4.x, v4.y, v4.z, v4.w};
            #pragma unroll
            for (int e = 0; e < 4; ++e){
                unsigned short h = f2bf(vv[e]);
                Ahi[row][c0 + q*4 + e] = h;
                Alo[row][c0 + q*4 + e] = f2bf(vv[e] - bf2f(h));
            }
        }
    }
    __syncthreads();
    // stage 1: wave w computes v-rows 16w..16w+15, 24 outputs (kz x re/im)
    int l = tid & 63, w = tid >> 6;
    int lr = l & 15, kg = l >> 4;
    int r0 = w << 4;
    f32x4 acc[2];
    acc[0] = (f32x4){0.f,0.f,0.f,0.f}; acc[1] = (f32x4){0.f,0.f,0.f,0.f};
    #pragma unroll
    for (int kc = 0; kc < 2; ++kc){
        int ko = kc*32 + kg*8;
        bf16x8 ah = *(const bf16x8*)&Ahi[r0 + lr][ko];
        bf16x8 al = *(const bf16x8*)&Alo[r0 + lr][ko];
        #pragma unroll
        for (int n = 0; n < 2; ++n){
            bf16x8 bh = *(const bf16x8*)&Bhi[n*16 + lr][ko];
            bf16x8 bl = *(const bf16x8*)&Blo[n*16 + lr][ko];
            acc[n] = __builtin_amdgcn_mfma_f32_16x16x32_bf16(ah, bh, acc[n], 0, 0, 0);
            acc[n] = __builtin_amdgcn_mfma_f32_16x16x32_bf16(ah, bl, acc[n], 0, 0, 0);
            acc[n] = __builtin_amdgcn_mfma_f32_16x16x32_bf16(al, bh, acc[n], 0, 0, 0);
        }
    }
    #pragma unroll
    for (int n = 0; n < 2; ++n){
        int o = n*16 + lr;
        if (o < 24){
            int kz = o >> 1;
            #pragma unroll
            for (int r = 0; r < 4; ++r){
                int v = r0 + kg*4 + r;
                if (o & 1) a2[kz][v].y = acc[n][r];
                else       a2[kz][v].x = acc[n][r];
            }
        }
    }
    __syncthreads();
    // stage 2: DFT over v -> X2[bc][kz][ky][s]
    for (int task = tid; task < 288; task += 256){
        int kz = task % 12;
        int ky = task / 12;
        int kya = (ky < 12) ? ky : ky + 40;
        float re = 0.f, im = 0.f;
        for (int v = 0; v < 64; ++v){
            float2 wv = wtab[(kya * v) & 63];
            float2 a  = a2[kz][v];
            re += a.x * wv.x + a.y * wv.y;
            im += a.y * wv.x - a.x * wv.y;
        }
        X2[((size_t)(bc*12 + kz) * 24 + ky) * 64 + s] = make_float2(re, im);
    }
}

// ---------------- forward DFT over s: X2[bc][kz][ky][s] -> X3[bc][kx][ky][kz]
__global__ __launch_bounds__(256) void k_fwdS(
    const float2* __restrict__ X2, float2* __restrict__ X3)
{
    __shared__ float2 cin[32][65];
    __shared__ float2 wtab[64];
    int tid = threadIdx.x;
    if (tid < 64){
        float sn, cs; sincosf((float)tid * TWOPI_64, &sn, &cs);
        wtab[tid] = make_float2(cs, sn);
    }
    int rbase = blockIdx.x * 32;   // rows (bc,kz,ky), 36864 total
    for (int i = tid; i < 2048; i += 256){
        int row = i >> 6, s = i & 63;
        cin[row][s] = X2[(size_t)(rbase + row) * 64 + s];
    }
    __syncthreads();
    int row = tid & 31;
    int r = rbase + row;
    int kxg = tid >> 5;       // 0..7 -> 3 kx each
    int kxs[3];
    #pragma unroll
    for (int j = 0; j < 3; ++j){ int kxi = kxg*3 + j; kxs[j] = (kxi < 12) ? kxi : kxi + 40; }
    float re[3] = {0,0,0}, im[3] = {0,0,0};
    for (int s = 0; s < 64; ++s){
        float2 cv = cin[row][s];
        #pragma unroll
        for (int j = 0; j < 3; ++j){
            float2 wv = wtab[(kxs[j] * s) & 63];
            re[j] += cv.x * wv.x + cv.y * wv.y;
            im[j] += cv.y * wv.x - cv.x * wv.y;
        }
    }
    int bc = r / 288; int kz = (r / 24) % 12; int ky = r % 24;
    #pragma unroll
    for (int j = 0; j < 3; ++j){
        int kxi = kxg*3 + j;
        X3[(size_t)bc * 6912 + (size_t)kxi * 288 + ky * 12 + kz] = make_float2(re[j], im[j]);
    }
}

// --------- per-mode channel mixing: coalesced W, X3 in regs, 4 o per block -
__global__ __launch_bounds__(256) void k_modemix(
    const float2* __restrict__ X3,
    const float* __restrict__ w1, const float* __restrict__ w2,
    const float* __restrict__ w3, const float* __restrict__ w4,
    int layer, float2* __restrict__ Y)
{
    __shared__ float2 wlds[32][64];   // [i][m], 16 KB
    int tid = threadIdx.x;
    int m   = tid & 63;
    int b   = tid >> 6;
    int corner = blockIdx.y >> 3;
    int o0     = (blockIdx.y & 7) * 4;
    int moff0  = blockIdx.x * 64;
    const float* wsrc = (corner==0 ? w1 : corner==1 ? w2 : corner==2 ? w3 : w4)
                        + (size_t)layer * 3538944;   // 32*32*1728*2
    int moff = moff0 + m;
    int m1  = moff / 144;
    int rem = moff - m1 * 144;
    int kx  = m1 + ((corner == 1 || corner == 3) ? 12 : 0);
    int mode_g = kx * 288 + rem + ((corner >= 2) ? 144 : 0);

    float xr[32], xi[32];
    const float2* xp = X3 + (size_t)b * 32 * 6912 + mode_g;
    #pragma unroll
    for (int i = 0; i < 32; ++i){
        float2 a = xp[(size_t)i * 6912];
        xr[i] = a.x; xi[i] = a.y;
    }
    for (int oo = 0; oo < 4; ++oo){
        int o = o0 + oo;
        __syncthreads();
        for (int j = tid; j < 2048; j += 256){
            int i = j >> 6, mm = j & 63;
            wlds[i][mm] = *(const float2*)&wsrc[((size_t)(i*32 + o) * 1728 + moff0 + mm) * 2];
        }
        __syncthreads();
        float re = 0.f, im = 0.f;
        #pragma unroll
        for (int i = 0; i < 32; ++i){
            float2 wv = wlds[i][m];
            re += xr[i]*wv.x - xi[i]*wv.y;
            im += xr[i]*wv.y + xi[i]*wv.x;
        }
        Y[(size_t)(b*32 + o) * 6912 + mode_g] = make_float2(re, im);
    }
}

// ---------------- inverse over s: Y[bo][kx][ky][kz] -> Z1[bo][kz][s][ky] ---
__global__ __launch_bounds__(256) void k_invS(
    const float2* __restrict__ Y, float2* __restrict__ Z1)
{
    __shared__ float2 yin[24][24];
    __shared__ float2 wtab[64];
    int tid = threadIdx.x;
    if (tid < 64){
        float sn, cs; sincosf((float)tid * TWOPI_64, &sn, &cs);
        wtab[tid] = make_float2(cs, sn);
    }
    int bo = blockIdx.x / 12;
    int kz = blockIdx.x % 12;
    for (int i = tid; i < 576; i += 256){
        int kx = i / 24, ky = i % 24;
        yin[kx][ky] = Y[(size_t)bo * 6912 + (size_t)kx * 288 + ky * 12 + kz];
    }
    __syncthreads();
    int s = tid & 63;
    int kyg = tid >> 6;   // 0..3 -> 6 ky each
    float re[6] = {0,0,0,0,0,0}, im[6] = {0,0,0,0,0,0};
    for (int kxi = 0; kxi < 24; ++kxi){
        int kxa = (kxi < 12) ? kxi : kxi + 40;
        float2 wv = wtab[(kxa * s) & 63];     // e^{+i theta}
        #pragma unroll
        for (int j = 0; j < 6; ++j){
            float2 a = yin[kxi][kyg*6 + j];
            re[j] += a.x * wv.x - a.y * wv.y;
            im[j] += a.x * wv.y + a.y * wv.x;
        }
    }
    #pragma unroll
    for (int j = 0; j < 6; ++j){
        int ky = kyg*6 + j;
        Z1[((size_t)(bo*12 + kz) * 64 + s) * 24 + ky] = make_float2(re[j], im[j]);
    }
}

// -- fused conv + inverse-v + inverse-t:  xA <- gelu(x1 + W*xA + cb) --------
// block = (b, s, vg); 256 pts (4 v x 64 t), all 32 channels; in-place safe.
__global__ __launch_bounds__(256) void k_cinvVT(
    const float* __restrict__ xin, const float2* __restrict__ Z1,
    const unsigned short* __restrict__ T2h, const unsigned short* __restrict__ T2l,
    const unsigned short* __restrict__ wcvh, const unsigned short* __restrict__ wcvl,
    const float* __restrict__ cb, int layer, float* __restrict__ xout)
{
    __shared__ __align__(16) unsigned short XT[2][256][40];  // [hi/lo][pt][i]; later x2s
    __shared__ __align__(16) unsigned short A2h[128][40], A2l[128][40];
    __shared__ float2 wtab[64];
    int tid = threadIdx.x;
    int vg = blockIdx.x & 15;
    int s  = (blockIdx.x >> 4) & 63;
    int b  = blockIdx.x >> 10;
    if (tid < 64){
        float sn, cs; sincosf((float)tid * TWOPI_64, &sn, &cs);
        wtab[tid] = make_float2(cs, sn);
    }
    {   // zero A2 pad cols 24..31
        int row = tid >> 1, half = tid & 1;
        us4 z = (us4){0,0,0,0};
        *(us4*)&A2h[row][24 + half*4] = z;
        *(us4*)&A2l[row][24 + half*4] = z;
    }
    // ---- phase 0: stage XT[pt][i] hi/lo (thread = pt, coalesced reads) ----
    {
        const float* xp = xin + (size_t)b*32*SVT + (size_t)s*VT + (size_t)vg*256 + tid;
        #pragma unroll
        for (int q = 0; q < 4; ++q){
            bf16x8 ph, pl;
            #pragma unroll
            for (int e = 0; e < 8; ++e){
                float v = xp[(size_t)(q*8 + e) * SVT];
                unsigned short h = f2bf(v);
                ph[e] = (short)h;
                pl[e] = (short)f2bf(v - bf2f(h));
            }
            *(bf16x8*)&XT[0][tid][q*8] = ph;
            *(bf16x8*)&XT[1][tid][q*8] = pl;
        }
    }
    __syncthreads();
    // ---- phase 1: inverse DFT over ky (fp32 VALU) -> A2 hi/lo -------------
    #pragma unroll
    for (int j = 0; j < 6; ++j){
        int task = tid + j*256;          // 1536 = 32o x 12kz x 4v
        int o = task / 48, rem = task % 48;
        int kz = rem >> 2, vloc = rem & 3;
        int v = vg*4 + vloc;
        const float2* zp = Z1 + ((size_t)((b*32 + o)*12 + kz) * 64 + s) * 24;
        float re = 0.f, im = 0.f;
        #pragma unroll
        for (int ky = 0; ky < 24; ++ky){
            int kya = (ky < 12) ? ky : ky + 40;
            float2 wv = wtab[(kya * v) & 63];
            float2 a = zp[ky];
            re += a.x * wv.x - a.y * wv.y;
            im += a.x * wv.y + a.y * wv.x;
        }
        int row = o*4 + vloc;
        unsigned short hr = f2bf(re), hm = f2bf(im);
        A2h[row][2*kz  ] = hr; A2l[row][2*kz  ] = f2bf(re - bf2f(hr));
        A2h[row][2*kz+1] = hm; A2l[row][2*kz+1] = f2bf(im - bf2f(hm));
    }
    __syncthreads();
    int l = tid & 63, w = tid >> 6, lr = l & 15, kg = l >> 4;
    // ---- phase 2: conv MFMA (split-bf16, 3 terms) -------------------------
    f32x4 dcv[2][4];
    #pragma unroll
    for (int ot = 0; ot < 2; ++ot){
        bf16x8 ah = *(const bf16x8*)&wcvh[layer*1024 + (ot*16 + lr)*32 + kg*8];
        bf16x8 al = *(const bf16x8*)&wcvl[layer*1024 + (ot*16 + lr)*32 + kg*8];
        #pragma unroll
        for (int ptt = 0; ptt < 4; ++ptt){
            bf16x8 bh = *(const bf16x8*)&XT[0][w*64 + ptt*16 + lr][kg*8];
            bf16x8 bl = *(const bf16x8*)&XT[1][w*64 + ptt*16 + lr][kg*8];
            f32x4 d = (f32x4){0.f,0.f,0.f,0.f};
            d = __builtin_amdgcn_mfma_f32_16x16x32_bf16(ah, bh, d, 0, 0, 0);
            d = __builtin_amdgcn_mfma_f32_16x16x32_bf16(ah, bl, d, 0, 0, 0);
            d = __builtin_amdgcn_mfma_f32_16x16x32_bf16(al, bh, d, 0, 0, 0);
            dcv[ot][ptt] = d;
        }
    }
    __syncthreads();   // all XT reads done -> overlay x2s
    float* x2s = (float*)&XT[0][0][0];   // [32][266] fp32
    #pragma unroll
    for (int ot = 0; ot < 2; ++ot)
        #pragma unroll
        for (int ptt = 0; ptt < 4; ++ptt)
            #pragma unroll
            for (int r = 0; r < 4; ++r)
                x2s[(ot*16 + kg*4 + r)*266 + w*64 + ptt*16 + lr] = dcv[ot][ptt][r];
    // ---- phase 3: inverse-t MFMA ------------------------------------------
    f32x4 dt[2][4];
    #pragma unroll
    for (int rt = 0; rt < 2; ++rt){
        bf16x8 ah = *(const bf16x8*)&A2h[w*32 + rt*16 + lr][kg*8];
        bf16x8 al = *(const bf16x8*)&A2l[w*32 + rt*16 + lr][kg*8];
        #pragma unroll
        for (int n = 0; n < 4; ++n){
            bf16x8 bh = *(const bf16x8*)&T2h[(n*16 + lr)*32 + kg*8];
            bf16x8 bl = *(const bf16x8*)&T2l[(n*16 + lr)*32 + kg*8];
            f32x4 d = (f32x4){0.f,0.f,0.f,0.f};
            d = __builtin_amdgcn_mfma_f32_16x16x32_bf16(ah, bh, d, 0, 0, 0);
            d = __builtin_amdgcn_mfma_f32_16x16x32_bf16(ah, bl, d, 0, 0, 0);
            d = __builtin_amdgcn_mfma_f32_16x16x32_bf16(al, bh, d, 0, 0, 0);
            dt[rt][n] = d;
        }
    }
    __syncthreads();   // x2s visible
    // ---- phase 4: epilogue gelu(x1 + x2 + cb) -> xout ---------------------
    size_t outb = (size_t)b*32*SVT + (size_t)s*VT + (size_t)vg*256;
    #pragma unroll
    for (int rt = 0; rt < 2; ++rt){
        int o = 8*w + rt*4 + kg;
        float cbv = cb[layer*32 + o];
        #pragma unroll
        for (int n = 0; n < 4; ++n){
            #pragma unroll
            for (int r = 0; r < 4; ++r){
                int pt = r*64 + n*16 + lr;
                float val = dt[rt][n][r] + x2s[o*266 + pt] + cbv;
                xout[outb + (size_t)o*SVT + pt] = gelu_f(val);
            }
        }
    }
}

// ------- fused skip MLP v5: 128 pts / 512 thr / 8 waves, full occupancy ----
// wave w owns p-tile w (points 16w..16w+15) in phase B; c-tile w in phase C.
template<int LAST>
__global__ __launch_bounds__(512, 8) void k_skip(
    const float* __restrict__ coords,
    const unsigned short* __restrict__ w1dup, const float* __restrict__ pbq,
    const unsigned short* __restrict__ w2bf, const float* __restrict__ s2b,
    const unsigned short* __restrict__ w3bf, const float* __restrict__ s3b,
    int layer, float* __restrict__ xio,
    const float* __restrict__ p1w, const float* __restrict__ p1b,
    const float* __restrict__ p2w, const float* __restrict__ p2b,
    float* __restrict__ out)
{
    __shared__ __align__(16) unsigned short A1[128][136];  // h1/h2 bf16; later overlay
    __shared__ __align__(16) unsigned short zst[8][16][8];

    int tid = threadIdx.x;
    size_t g0 = (size_t)blockIdx.x * 128;
    int b = (int)(g0 >> 18);
    const unsigned short* w2g = w2bf + (size_t)layer * 16384;   // [c][k]
    const unsigned short* w3g = w3bf + (size_t)layer * 4096;    // [c2][k]
    const unsigned short* w1g = w1dup + (size_t)layer * 1024;   // [h][8]
    const float* pbg = pbq + layer*512 + b*128;
    const float* b2g = s2b + layer*128;

    int l  = tid & 63;
    int w  = tid >> 6;        // 0..7
    int lr = l & 15;
    int kg = l >> 4;

    // ---- stage z (hi/lo bf16) for wave's 16 points; wave-local ------------
    if (l < 16){
        size_t g = g0 + (size_t)w*16 + l;
        float z0 = coords[g*3+0], z1 = coords[g*3+1], z2 = coords[g*3+2];
        unsigned short h0 = f2bf(z0), h1 = f2bf(z1), h2 = f2bf(z2);
        bf16x8 pk;
        pk[0] = (short)h0; pk[1] = (short)h1; pk[2] = (short)h2; pk[3] = 0;
        pk[4] = (short)f2bf(z0 - bf2f(h0));
        pk[5] = (short)f2bf(z1 - bf2f(h1));
        pk[6] = (short)f2bf(z2 - bf2f(h2));
        pk[7] = 0;
        *(bf16x8*)&zst[w][l][0] = pk;
    }
    bf16x8 bz;
    if (kg == 0) bz = *(const bf16x8*)&zst[w][lr][0];
    else         bz = (bf16x8){0,0,0,0,0,0,0,0};

    // ---- phase B: h1 = gelu(z@w1 + pb) via MFMA, D[h][p] ------------------
    {
        f32x4 accB[8];
        #pragma unroll
        for (int m = 0; m < 8; ++m) accB[m] = (f32x4){0.f,0.f,0.f,0.f};
        #pragma unroll
        for (int m = 0; m < 8; ++m){
            bf16x8 af = *(const bf16x8*)&w1g[(m*16 + lr)*8];
            accB[m] = __builtin_amdgcn_mfma_f32_16x16x32_bf16(af, bz, accB[m], 0, 0, 0);
        }
        #pragma unroll
        for (int m = 0; m < 8; ++m){
            int c0 = m*16 + kg*4;
            float4 bb = *(const float4*)&pbg[c0];
            us4 pk4;
            pk4[0] = f2bf(gelu_f(accB[m][0] + bb.x));
            pk4[1] = f2bf(gelu_f(accB[m][1] + bb.y));
            pk4[2] = f2bf(gelu_f(accB[m][2] + bb.z));
            pk4[3] = f2bf(gelu_f(accB[m][3] + bb.w));
            *(us4*)&A1[w*16 + lr][c0] = pk4;
        }
    }
    __syncthreads();   // h1 visible to all waves

    // ---- phase C: h2pre = h1 @ w2 (MFMA, swapped -> D[c][p]) --------------
    // wave w owns c-tile w over all 8 p-tiles
    f32x4 accC[8];
    #pragma unroll
    for (int pt = 0; pt < 8; ++pt) accC[pt] = (f32x4){0.f,0.f,0.f,0.f};
    #pragma unroll
    for (int kc = 0; kc < 4; ++kc){
        int ko = kc*32 + kg*8;
        bf16x8 a0 = *(const bf16x8*)&w2g[(w*16 + lr)*128 + ko];
        #pragma unroll
        for (int pt = 0; pt < 8; ++pt){
            bf16x8 bb = *(const bf16x8*)&A1[pt*16 + lr][ko];
            accC[pt] = __builtin_amdgcn_mfma_f32_16x16x32_bf16(a0, bb, accC[pt], 0, 0, 0);
        }
    }
    __syncthreads();   // all h1 reads done -> safe to overwrite A1 with h2
    {
        int c0 = w*16 + kg*4;
        float4 bb = *(const float4*)&b2g[c0];
        #pragma unroll
        for (int pt = 0; pt < 8; ++pt){
            us4 pk4;
            pk4[0] = f2bf(gelu_f(accC[pt][0] + bb.x));
            pk4[1] = f2bf(gelu_f(accC[pt][1] + bb.y));
            pk4[2] = f2bf(gelu_f(accC[pt][2] + bb.z));
            pk4[3] = f2bf(gelu_f(accC[pt][3] + bb.w));
            *(us4*)&A1[pt*16 + lr][c0] = pk4;
        }
    }
    __syncthreads();   // h2 visible

    // ---- phase D: out = h2 @ w3 (MFMA, unswapped -> D[p][c2]) -------------
    // wave w: c2-tile = w&1, p-tiles {(w>>1)*2, +1}
    int nD  = w & 1;
    int pt0 = (w >> 1) * 2;
    float b3v = s3b[layer*32 + nD*16 + lr];
    f32x4 c3[2];
    c3[0] = (f32x4){0.f,0.f,0.f,0.f}; c3[1] = (f32x4){0.f,0.f,0.f,0.f};
    #pragma unroll
    for (int kc = 0; kc < 4; ++kc){
        int ko = kc*32 + kg*8;
        bf16x8 bw3 = *(const bf16x8*)&w3g[(nD*16 + lr)*128 + ko];
        bf16x8 aa0 = *(const bf16x8*)&A1[(pt0    )*16 + lr][ko];
        bf16x8 aa1 = *(const bf16x8*)&A1[(pt0 + 1)*16 + lr][ko];
        c3[0] = __builtin_amdgcn_mfma_f32_16x16x32_bf16(aa0, bw3, c3[0], 0, 0, 0);
        c3[1] = __builtin_amdgcn_mfma_f32_16x16x32_bf16(aa1, bw3, c3[1], 0, 0, 0);
    }
    __syncthreads();   // all h2 reads done -> A1 free for overlay

    float* outsT = (float*)&A1[0][0];      // [32][132] fp32, transposed
    float* hs    = outsT + 4224;           // [128][17]
    float* p1wS  = outsT + 6400;           // [512]
    float* smB   = outsT + 6912;           // 16 b1 | 16 p2w | 1 p2b
    {
        int c2 = nD*16 + lr;
        #pragma unroll
        for (int q = 0; q < 2; ++q){
            int p0 = (pt0 + q)*16 + kg*4;
            float4 v4;
            v4.x = c3[q][0] + b3v; v4.y = c3[q][1] + b3v;
            v4.z = c3[q][2] + b3v; v4.w = c3[q][3] + b3v;
            *(float4*)&outsT[c2*132 + p0] = v4;
        }
    }
    if (LAST){
        for (int i = tid; i < 512; i += 512) p1wS[i] = p1w[i];
        if (tid < 512) { if (tid < 512 && tid < 512) {} }
        for (int i = tid; i < 512; i += 512) {}
        if (tid < 16){ smB[tid] = p1b[tid]; smB[16 + tid] = p2w[tid]; }
        if (tid == 32) smB[32] = p2b[0];
        if (tid >= 64 && tid < 64+512-512) {}
        // stage p1w with all threads (512 >= 512: one element each)
        if (tid < 512 && tid < 512) p1wS[tid] = p1w[tid];
    }
    __syncthreads();

    // ---- rmw: xsum = xio + skip ------------------------------------------
    {
        int c  = tid >> 4;        // 0..31
        int pg = tid & 15;        // 8 floats each
        size_t prel = (g0 & (size_t)(SVT - 1)) + (size_t)pg*8;
        float* gp = xio + (((size_t)(b*32 + c)) << 18) + prel;
        float* op = &outsT[c*132 + pg*8];
        #pragma unroll
        for (int i = 0; i < 8; i += 4){
            float4 xv = *(const float4*)&gp[i];
            float4 ov = *(const float4*)&op[i];
            ov.x += xv.x; ov.y += xv.y; ov.z += xv.z; ov.w += xv.w;
            if (LAST) *(float4*)&op[i] = ov;     // keep xsum in LDS
            else      *(float4*)&gp[i] = ov;     // write back to global
        }
    }
    if (LAST){
        __syncthreads();
        {
            int p  = tid & 127;
            int jq = tid >> 7;    // 0..3 -> 4 j each
            float h[4];
            #pragma unroll
            for (int j = 0; j < 4; ++j) h[j] = smB[jq*4 + j];
            for (int c = 0; c < 32; ++c){
                float xv = outsT[c*132 + p];
                #pragma unroll
                for (int j = 0; j < 4; ++j) h[j] += xv * p1wS[c*16 + jq*4 + j];
            }
            #pragma unroll
            for (int j = 0; j < 4; ++j) hs[p*17 + jq*4 + j] = h[j];
        }
        __syncthreads();
        if (tid < 128){
            float acc = smB[32];
            #pragma unroll
            for (int j = 0; j < 16; ++j) acc += gelu_f(hs[tid*17 + j]) * smB[16 + j];
            out[g0 + tid] = acc;
        }
    }
}

extern "C" void kernel_launch(void* const* d_in, const int* in_sizes, int n_in,
                              void* d_out, int out_size, void* d_ws, size_t ws_size,
                              hipStream_t stream)
{
    (void)in_sizes; (void)n_in; (void)out_size; (void)ws_size;
    const float* coords = (const float*)d_in[0];
    const float* params = (const float*)d_in[1];
    const float* lift_w = (const float*)d_in[2];
    const float* lift_b = (const float*)d_in[3];
    const float* sw1    = (const float*)d_in[4];
    const float* sw2    = (const float*)d_in[5];
    const float* sw3    = (const float*)d_in[6];
    const float* sw4    = (const float*)d_in[7];
    const float* conv_w = (const float*)d_in[8];
    const float* conv_b = (const float*)d_in[9];
    const float* s1w    = (const float*)d_in[10];
    const float* s1b    = (const float*)d_in[11];
    const float* s2w    = (const float*)d_in[12];
    const float* s2b    = (const float*)d_in[13];
    const float* s3w    = (const float*)d_in[14];
    const float* s3b    = (const float*)d_in[15];
    const float* p1w    = (const float*)d_in[16];
    const float* p1b    = (const float*)d_in[17];
    const float* p2w    = (const float*)d_in[18];
    const float* p2b    = (const float*)d_in[19];
    float* out = (float*)d_out;

    char* ws = (char*)d_ws;
    float*  xA = (float*)(ws);                                    // 134,217,728
    float2* X2 = (float2*)(ws + 134217728ull);                    //  18,874,368 (also Z1)
    float2* X3 = (float2*)(ws + 153092096ull);                    //   7,077,888
    float2* Yb = (float2*)(ws + 160169984ull);                    //   7,077,888
    unsigned short* w2bf  = (unsigned short*)(ws + 167247872ull); //     131,072
    unsigned short* w3bf  = (unsigned short*)(ws + 167378944ull); //      32,768
    unsigned short* tdft  = (unsigned short*)(ws + 167411712ull); //       8,192
    unsigned short* T1h   = (unsigned short*)(ws + 167419904ull); //      16,384
    unsigned short* T1l   = (unsigned short*)(ws + 167436288ull); //      16,384
    unsigned short* T2h   = (unsigned short*)(ws + 167452672ull); //       4,096
    unsigned short* T2l   = (unsigned short*)(ws + 167456768ull); //       4,096
    float*          pbq   = (float*)(ws + 167460864ull);          //       8,192
    unsigned short* w1dup = (unsigned short*)(ws + 167469056ull); //       8,192
    unsigned short* wcvh  = (unsigned short*)(ws + 167477248ull); //       8,192
    unsigned short* wcvl  = (unsigned short*)(ws + 167485440ull); //       8,192
    // total 167,493,632 B

    k_prep<<<408, 256, 0, stream>>>(params, s1w, s1b, s2w, s3w, conv_w,
                                    w2bf, w3bf, tdft, T1h, T1l, T2h, T2l,
                                    pbq, w1dup, wcvh, wcvl);
    k_lift<<<4096, 256, 0, stream>>>(coords, params, lift_w, lift_b, xA);

    for (int l = 0; l < NLAY; ++l){
        k_fwdTV<<<8192, 256, 0, stream>>>(xA, tdft, X2);
        k_fwdS<<<1152, 256, 0, stream>>>(X2, X3);
        dim3 gmm(27, 32);
        k_modemix<<<gmm, 256, 0, stream>>>(X3, sw1, sw2, sw3, sw4, l, Yb);
        k_invS<<<1536, 256, 0, stream>>>(Yb, X2);          // Z1 overlays X2
        k_cinvVT<<<4096, 256, 0, stream>>>(xA, X2, T2h, T2l, wcvh, wcvl,
                                           conv_b, l, xA);
        if (l < NLAY - 1)
            k_skip<0><<<8192, 512, 0, stream>>>(coords, w1dup, pbq,
                w2bf, s2b, w3bf, s3b, l, xA, p1w, p1b, p2w, p2b, out);
        else
            k_skip<1><<<8192, 512, 0, stream>>>(coords, w1dup, pbq,
                w2bf, s2b, w3bf, s3b, l, xA, p1w, p1b, p2w, p2b, out);
    }
}

// Round 12
// 1499.741 us; speedup vs baseline: 1.2808x; 1.0356x over previous
//
#include <hip/hip_runtime.h>
#include <hip/hip_bf16.h>
#include <math.h>

#define NB   4
#define NC   32
#define SVT  262144      // 64^3
#define VT   4096        // 64*64
#define NLAY 4
#define TWOPI_64 0.09817477042468103f

typedef __attribute__((ext_vector_type(8))) short bf16x8;
typedef __attribute__((ext_vector_type(4))) float f32x4;
typedef __attribute__((ext_vector_type(4))) unsigned short us4;

// tanh-form GELU via hw exp2/rcp; |err| vs exact erf-GELU < ~2.5e-4
__device__ __forceinline__ float gelu_f(float x){
    float x2 = x * x;
    float u  = x * __builtin_fmaf(-0.10294322f, x2, -2.30220795f);
    float e  = __builtin_amdgcn_exp2f(u);
    return x * __builtin_amdgcn_rcpf(1.0f + e);
}

__device__ __forceinline__ unsigned short f2bf(float f){
    union { __hip_bfloat16 h; unsigned short u; } cv;
    cv.h = __float2bfloat16(f);
    return cv.u;
}
__device__ __forceinline__ float bf2f(unsigned short u){
    return __uint_as_float(((unsigned int)u) << 16);
}

// 8-bf16 fragment from 8B-aligned LDS (two ds_read_b64)
__device__ __forceinline__ bf16x8 lds8(const unsigned short* p){
    us4 a = *(const us4*)p;
    us4 b = *(const us4*)(p + 4);
    bf16x8 r;
    r[0]=(short)a[0]; r[1]=(short)a[1]; r[2]=(short)a[2]; r[3]=(short)a[3];
    r[4]=(short)b[0]; r[5]=(short)b[1]; r[6]=(short)b[2]; r[7]=(short)b[3];
    return r;
}

// ------------- weight prep: bf16 transposes + twiddle tables + pb ---------
__global__ __launch_bounds__(256) void k_prep(
    const float* __restrict__ params,
    const float* __restrict__ s1w, const float* __restrict__ s1b,
    const float* __restrict__ s2w, const float* __restrict__ s3w,
    const float* __restrict__ conv_w,
    unsigned short* __restrict__ w2bf,   // [4][c 128][k 128]
    unsigned short* __restrict__ w3bf,   // [4][c2 32][k 128]
    unsigned short* __restrict__ tdft,   // [2(hi,lo)][32 o][64 t]
    unsigned short* __restrict__ T1h, unsigned short* __restrict__ T1l, // [128][64]
    unsigned short* __restrict__ T2h, unsigned short* __restrict__ T2l, // [64][32]
    float* __restrict__ pbq,             // [4 l][4 b][128]
    unsigned short* __restrict__ w1dup,  // [4 l][128][8]
    unsigned short* __restrict__ wcvh, unsigned short* __restrict__ wcvl, // [4][32][32]
    unsigned short* __restrict__ T3h, unsigned short* __restrict__ T3l)  // [48][128]
{
    int g = blockIdx.x * 256 + threadIdx.x;
    if (g < 65536){
        int l = g >> 14, r = g & 16383;
        int c = r >> 7, k = r & 127;
        w2bf[g] = f2bf(s2w[l*16384 + k*128 + c]);
        return;
    }
    g -= 65536;
    if (g < 16384){
        int l = g >> 12, r = g & 4095;
        int c2 = r >> 7, k = r & 127;
        w3bf[g] = f2bf(s3w[l*4096 + k*32 + c2]);
        return;
    }
    g -= 16384;
    if (g < 2048){
        int o = g >> 6, t = g & 63;
        float val = 0.f;
        if (o < 24){
            int kz = o >> 1;
            float ang = (float)((kz * t) & 63) * TWOPI_64;
            float sn, cs; sincosf(ang, &sn, &cs);
            val = (o & 1) ? -sn : cs;      // forward DFT: e^{-i theta}
        }
        unsigned short h = f2bf(val);
        tdft[g]        = h;
        tdft[2048 + g] = f2bf(val - bf2f(h));
        return;
    }
    g -= 2048;
    if (g < 8192){           // T1 (unused; kept for layout stability)
        int col = g >> 6, k1 = g & 63;
        int v = col >> 1, pout = col & 1;
        float val = 0.f;
        if (k1 < 48){
            int ky = k1 >> 1, pin = k1 & 1;
            int kya = (ky < 12) ? ky : ky + 40;
            float ang = (float)((kya * v) & 63) * TWOPI_64;
            float sn, cs; sincosf(ang, &sn, &cs);
            val = pout == 0 ? (pin == 0 ? cs : -sn) : (pin == 0 ? sn : cs);
        }
        unsigned short h = f2bf(val);
        T1h[g] = h;
        T1l[g] = f2bf(val - bf2f(h));
        return;
    }
    g -= 8192;
    if (g < 2048){           // T2: real inverse over kz -> t (norm + x2 folded)
        int t = g >> 5, k2 = g & 31;
        float val = 0.f;
        if (k2 < 24){
            int kz = k2 >> 1, part = k2 & 1;
            float wk = (kz == 0) ? 1.f : 2.f;
            float ang = (float)((kz * t) & 63) * TWOPI_64;
            float sn, cs; sincosf(ang, &sn, &cs);
            val = (part ? -sn : cs) * wk * (1.f / 262144.f);
        }
        unsigned short h = f2bf(val);
        T2h[g] = h;
        T2l[g] = f2bf(val - bf2f(h));
        return;
    }
    g -= 2048;
    if (g < 2048){           // pbq[l][b][h]
        int l = g >> 9, b = (g >> 7) & 3, h = g & 127;
        float acc = s1b[l*128 + h];
        #pragma unroll
        for (int j = 0; j < 6; ++j)
            acc += params[b*6 + j] * bf2f(f2bf(s1w[l*1152 + (3 + j)*128 + h]));
        pbq[g] = acc;
        return;
    }
    g -= 2048;
    if (g < 4096){           // w1dup[l][h][slot]: rows 0-2 dup in 0-2 & 4-6
        int l = g >> 10, rem = g & 1023;
        int h = rem >> 3, slot = rem & 7;
        float val = 0.f;
        if (slot != 3 && slot != 7){
            int row = (slot < 3) ? slot : slot - 4;
            val = bf2f(f2bf(s1w[l*1152 + row*128 + h]));
        }
        w1dup[g] = f2bf(val);
        return;
    }
    g -= 4096;
    if (g < 4096){           // conv weights hi/lo, [l][o][i]
        float val = conv_w[g];
        unsigned short h = f2bf(val);
        wcvh[g] = h;
        wcvl[g] = f2bf(val - bf2f(h));
        return;
    }
    g -= 4096;
    if (g < 6144){           // T3: forward v-DFT, [48 (2ky+pin)][128 (2v+part)]
        int row = g >> 7, k = g & 127;
        int ky = row >> 1, pin = row & 1;
        int v = k >> 1, part = k & 1;
        int kya = (ky < 12) ? ky : ky + 40;
        float ang = (float)((kya * v) & 63) * TWOPI_64;
        float sn, cs; sincosf(ang, &sn, &cs);
        float val = (pin == 0) ? (part == 0 ? cs : sn)
                               : (part == 0 ? -sn : cs);
        unsigned short h = f2bf(val);
        T3h[g] = h;
        T3l[g] = f2bf(val - bf2f(h));
    }
}

// ---------------- lift: x = z @ lift_w + lift_b, layout [B,C,S,V,T] -------
__global__ __launch_bounds__(256) void k_lift(
    const float* __restrict__ coords, const float* __restrict__ params,
    const float* __restrict__ lw, const float* __restrict__ lb,
    float* __restrict__ x)
{
    size_t g = (size_t)blockIdx.x * 256 + threadIdx.x;   // 0..1048575
    int b = (int)(g >> 18);
    size_t p = g & (size_t)(SVT - 1);
    float z[9];
    z[0] = coords[g*3+0]; z[1] = coords[g*3+1]; z[2] = coords[g*3+2];
    #pragma unroll
    for (int j = 0; j < 6; ++j) z[3+j] = params[b*6+j];
    #pragma unroll
    for (int c = 0; c < 32; ++c){
        float acc = lb[c];
        #pragma unroll
        for (int j = 0; j < 9; ++j) acc += z[j] * lw[j*32 + c];
        x[(size_t)(b*32 + c) * SVT + p] = acc;
    }
}

// --- fused forward DFT t then v (both MFMA): x -> X2[bc][kz][ky][s] --------
__global__ __launch_bounds__(256) void k_fwdTV(
    const float* __restrict__ x, const unsigned short* __restrict__ tdft,
    const unsigned short* __restrict__ T3h, const unsigned short* __restrict__ T3l,
    float2* __restrict__ X2)
{
    __shared__ __align__(16) unsigned short Ahi[64][72], Alo[64][72];
    __shared__ __align__(16) unsigned short Bhi[32][72], Blo[32][72];
    __shared__ __align__(16) unsigned short Ast_h[16][136], Ast_l[16][136];
    int tid = threadIdx.x;
    int bc = blockIdx.x >> 6;
    int s  = blockIdx.x & 63;
    for (int i = tid; i < 2048; i += 256){
        int o = i >> 6, t = i & 63;
        Bhi[o][t] = tdft[i];
        Blo[o][t] = tdft[2048 + i];
    }
    // zero Ast rows 12..15 (M-pad for stage-2 A)
    for (int i = tid; i < 544; i += 256){
        int r = 12 + i / 136, c = i % 136;
        Ast_h[r][c] = 0; Ast_l[r][c] = 0;
    }
    // stage x -> hi/lo bf16
    {
        int row = tid >> 2, c0 = (tid & 3) << 4;
        const float* src = x + (size_t)bc * SVT + (size_t)s * VT + row*64 + c0;
        #pragma unroll
        for (int q = 0; q < 4; ++q){
            float4 v4 = *(const float4*)&src[q*4];
            float vv[4] = {v4.x, v4.y, v4.z, v4.w};
            #pragma unroll
            for (int e = 0; e < 4; ++e){
                unsigned short h = f2bf(vv[e]);
                Ahi[row][c0 + q*4 + e] = h;
                Alo[row][c0 + q*4 + e] = f2bf(vv[e] - bf2f(h));
            }
        }
    }
    __syncthreads();
    // stage 1 (t-DFT, MFMA): wave w computes v-rows 16w..16w+15, o = kz x part
    int l = tid & 63, w = tid >> 6;
    int lr = l & 15, kg = l >> 4;
    int r0 = w << 4;
    f32x4 acc[2];
    acc[0] = (f32x4){0.f,0.f,0.f,0.f}; acc[1] = (f32x4){0.f,0.f,0.f,0.f};
    #pragma unroll
    for (int kc = 0; kc < 2; ++kc){
        int ko = kc*32 + kg*8;
        bf16x8 ah = *(const bf16x8*)&Ahi[r0 + lr][ko];
        bf16x8 al = *(const bf16x8*)&Alo[r0 + lr][ko];
        #pragma unroll
        for (int n = 0; n < 2; ++n){
            bf16x8 bh = *(const bf16x8*)&Bhi[n*16 + lr][ko];
            bf16x8 bl = *(const bf16x8*)&Blo[n*16 + lr][ko];
            acc[n] = __builtin_amdgcn_mfma_f32_16x16x32_bf16(ah, bh, acc[n], 0, 0, 0);
            acc[n] = __builtin_amdgcn_mfma_f32_16x16x32_bf16(ah, bl, acc[n], 0, 0, 0);
            acc[n] = __builtin_amdgcn_mfma_f32_16x16x32_bf16(al, bh, acc[n], 0, 0, 0);
        }
    }
    // epilogue: Ast[kz][2v+part] hi/lo (stage-2 A operand)
    #pragma unroll
    for (int n = 0; n < 2; ++n){
        int o = n*16 + lr;
        if (o < 24){
            int kz = o >> 1, part = o & 1;
            #pragma unroll
            for (int r = 0; r < 4; ++r){
                int v = r0 + kg*4 + r;
                float val = acc[n][r];
                unsigned short h = f2bf(val);
                Ast_h[kz][2*v + part] = h;
                Ast_l[kz][2*v + part] = f2bf(val - bf2f(h));
            }
        }
    }
    __syncthreads();
    // stage 2 (v-DFT, MFMA): waves 0..2 -> n-tile w; D[kz][2ky+pin]
    if (w < 3){
        f32x4 d = (f32x4){0.f,0.f,0.f,0.f};
        #pragma unroll
        for (int kc = 0; kc < 4; ++kc){
            int ko = kc*32 + kg*8;
            bf16x8 ah = lds8(&Ast_h[lr][ko]);
            bf16x8 al = lds8(&Ast_l[lr][ko]);
            bf16x8 bh = *(const bf16x8*)&T3h[(w*16 + lr)*128 + ko];
            bf16x8 bl = *(const bf16x8*)&T3l[(w*16 + lr)*128 + ko];
            d = __builtin_amdgcn_mfma_f32_16x16x32_bf16(ah, bh, d, 0, 0, 0);
            d = __builtin_amdgcn_mfma_f32_16x16x32_bf16(ah, bl, d, 0, 0, 0);
            d = __builtin_amdgcn_mfma_f32_16x16x32_bf16(al, bh, d, 0, 0, 0);
        }
        int colg = w*16 + lr;
        int ky = colg >> 1, pin = colg & 1;
        float* xf = (float*)X2;
        #pragma unroll
        for (int r = 0; r < 4; ++r){
            int kz = kg*4 + r;
            if (kz < 12)
                xf[(((size_t)(bc*12 + kz) * 24 + ky) * 64 + s) * 2 + pin] = d[r];
        }
    }
}

// ---------------- forward DFT over s: X2[bc][kz][ky][s] -> X3[bc][kx][ky][kz]
__global__ __launch_bounds__(256) void k_fwdS(
    const float2* __restrict__ X2, float2* __restrict__ X3)
{
    __shared__ float2 cin[32][65];
    __shared__ float2 wtab[64];
    int tid = threadIdx.x;
    if (tid < 64){
        float sn, cs; sincosf((float)tid * TWOPI_64, &sn, &cs);
        wtab[tid] = make_float2(cs, sn);
    }
    int rbase = blockIdx.x * 32;   // rows (bc,kz,ky), 36864 total
    for (int i = tid; i < 2048; i += 256){
        int row = i >> 6, s = i & 63;
        cin[row][s] = X2[(size_t)(rbase + row) * 64 + s];
    }
    __syncthreads();
    int row = tid & 31;
    int r = rbase + row;
    int kxg = tid >> 5;       // 0..7 -> 3 kx each
    int kxs[3];
    #pragma unroll
    for (int j = 0; j < 3; ++j){ int kxi = kxg*3 + j; kxs[j] = (kxi < 12) ? kxi : kxi + 40; }
    float re[3] = {0,0,0}, im[3] = {0,0,0};
    for (int s = 0; s < 64; ++s){
        float2 cv = cin[row][s];
        #pragma unroll
        for (int j = 0; j < 3; ++j){
            float2 wv = wtab[(kxs[j] * s) & 63];
            re[j] += cv.x * wv.x + cv.y * wv.y;
            im[j] += cv.y * wv.x - cv.x * wv.y;
        }
    }
    int bc = r / 288; int kz = (r / 24) % 12; int ky = r % 24;
    #pragma unroll
    for (int j = 0; j < 3; ++j){
        int kxi = kxg*3 + j;
        X3[(size_t)bc * 6912 + (size_t)kxi * 288 + ky * 12 + kz] = make_float2(re[j], im[j]);
    }
}

// --------- per-mode channel mixing: coalesced W, X3 in regs, 4 o per block -
__global__ __launch_bounds__(256) void k_modemix(
    const float2* __restrict__ X3,
    const float* __restrict__ w1, const float* __restrict__ w2,
    const float* __restrict__ w3, const float* __restrict__ w4,
    int layer, float2* __restrict__ Y)
{
    __shared__ float2 wlds[32][64];   // [i][m], 16 KB
    int tid = threadIdx.x;
    int m   = tid & 63;
    int b   = tid >> 6;
    int corner = blockIdx.y >> 3;
    int o0     = (blockIdx.y & 7) * 4;
    int moff0  = blockIdx.x * 64;
    const float* wsrc = (corner==0 ? w1 : corner==1 ? w2 : corner==2 ? w3 : w4)
                        + (size_t)layer * 3538944;   // 32*32*1728*2
    int moff = moff0 + m;
    int m1  = moff / 144;
    int rem = moff - m1 * 144;
    int kx  = m1 + ((corner == 1 || corner == 3) ? 12 : 0);
    int mode_g = kx * 288 + rem + ((corner >= 2) ? 144 : 0);

    float xr[32], xi[32];
    const float2* xp = X3 + (size_t)b * 32 * 6912 + mode_g;
    #pragma unroll
    for (int i = 0; i < 32; ++i){
        float2 a = xp[(size_t)i * 6912];
        xr[i] = a.x; xi[i] = a.y;
    }
    for (int oo = 0; oo < 4; ++oo){
        int o = o0 + oo;
        __syncthreads();
        for (int j = tid; j < 2048; j += 256){
            int i = j >> 6, mm = j & 63;
            wlds[i][mm] = *(const float2*)&wsrc[((size_t)(i*32 + o) * 1728 + moff0 + mm) * 2];
        }
        __syncthreads();
        float re = 0.f, im = 0.f;
        #pragma unroll
        for (int i = 0; i < 32; ++i){
            float2 wv = wlds[i][m];
            re += xr[i]*wv.x - xi[i]*wv.y;
            im += xr[i]*wv.y + xi[i]*wv.x;
        }
        Y[(size_t)(b*32 + o) * 6912 + mode_g] = make_float2(re, im);
    }
}

// ---------------- inverse over s: Y[bo][kx][ky][kz] -> Z1[bo][kz][s][ky] ---
__global__ __launch_bounds__(256) void k_invS(
    const float2* __restrict__ Y, float2* __restrict__ Z1)
{
    __shared__ float2 yin[24][24];
    __shared__ float2 wtab[64];
    int tid = threadIdx.x;
    if (tid < 64){
        float sn, cs; sincosf((float)tid * TWOPI_64, &sn, &cs);
        wtab[tid] = make_float2(cs, sn);
    }
    int bo = blockIdx.x / 12;
    int kz = blockIdx.x % 12;
    for (int i = tid; i < 576; i += 256){
        int kx = i / 24, ky = i % 24;
        yin[kx][ky] = Y[(size_t)bo * 6912 + (size_t)kx * 288 + ky * 12 + kz];
    }
    __syncthreads();
    int s = tid & 63;
    int kyg = tid >> 6;   // 0..3 -> 6 ky each
    float re[6] = {0,0,0,0,0,0}, im[6] = {0,0,0,0,0,0};
    for (int kxi = 0; kxi < 24; ++kxi){
        int kxa = (kxi < 12) ? kxi : kxi + 40;
        float2 wv = wtab[(kxa * s) & 63];     // e^{+i theta}
        #pragma unroll
        for (int j = 0; j < 6; ++j){
            float2 a = yin[kxi][kyg*6 + j];
            re[j] += a.x * wv.x - a.y * wv.y;
            im[j] += a.x * wv.y + a.y * wv.x;
        }
    }
    #pragma unroll
    for (int j = 0; j < 6; ++j){
        int ky = kyg*6 + j;
        Z1[((size_t)(bo*12 + kz) * 64 + s) * 24 + ky] = make_float2(re[j], im[j]);
    }
}

// -- fused conv + inverse-v + inverse-t:  xA <- gelu(x1 + W*xA + cb) --------
// block = (b, s, vg); 256 pts (4 v x 64 t), all 32 channels; in-place safe.
__global__ __launch_bounds__(256) void k_cinvVT(
    const float* __restrict__ xin, const float2* __restrict__ Z1,
    const unsigned short* __restrict__ T2h, const unsigned short* __restrict__ T2l,
    const unsigned short* __restrict__ wcvh, const unsigned short* __restrict__ wcvl,
    const float* __restrict__ cb, int layer, float* __restrict__ xout)
{
    __shared__ __align__(16) unsigned short XT[2][256][40];  // [hi/lo][pt][i]; later x2s
    __shared__ __align__(16) unsigned short A2h[128][40], A2l[128][40];
    __shared__ float2 wtab[64];
    int tid = threadIdx.x;
    int vg = blockIdx.x & 15;
    int s  = (blockIdx.x >> 4) & 63;
    int b  = blockIdx.x >> 10;
    if (tid < 64){
        float sn, cs; sincosf((float)tid * TWOPI_64, &sn, &cs);
        wtab[tid] = make_float2(cs, sn);
    }
    {   // zero A2 pad cols 24..31
        int row = tid >> 1, half = tid & 1;
        us4 z = (us4){0,0,0,0};
        *(us4*)&A2h[row][24 + half*4] = z;
        *(us4*)&A2l[row][24 + half*4] = z;
    }
    // ---- phase 0: stage XT[pt][i] hi/lo (thread = pt, coalesced reads) ----
    {
        const float* xp = xin + (size_t)b*32*SVT + (size_t)s*VT + (size_t)vg*256 + tid;
        #pragma unroll
        for (int q = 0; q < 4; ++q){
            bf16x8 ph, pl;
            #pragma unroll
            for (int e = 0; e < 8; ++e){
                float v = xp[(size_t)(q*8 + e) * SVT];
                unsigned short h = f2bf(v);
                ph[e] = (short)h;
                pl[e] = (short)f2bf(v - bf2f(h));
            }
            *(bf16x8*)&XT[0][tid][q*8] = ph;
            *(bf16x8*)&XT[1][tid][q*8] = pl;
        }
    }
    __syncthreads();
    // ---- phase 1: inverse DFT over ky (fp32 VALU) -> A2 hi/lo -------------
    #pragma unroll
    for (int j = 0; j < 6; ++j){
        int task = tid + j*256;          // 1536 = 32o x 12kz x 4v
        int o = task / 48, rem = task % 48;
        int kz = rem >> 2, vloc = rem & 3;
        int v = vg*4 + vloc;
        const float2* zp = Z1 + ((size_t)((b*32 + o)*12 + kz) * 64 + s) * 24;
        float re = 0.f, im = 0.f;
        #pragma unroll
        for (int ky = 0; ky < 24; ++ky){
            int kya = (ky < 12) ? ky : ky + 40;
            float2 wv = wtab[(kya * v) & 63];
            float2 a = zp[ky];
            re += a.x * wv.x - a.y * wv.y;
            im += a.x * wv.y + a.y * wv.x;
        }
        int row = o*4 + vloc;
        unsigned short hr = f2bf(re), hm = f2bf(im);
        A2h[row][2*kz  ] = hr; A2l[row][2*kz  ] = f2bf(re - bf2f(hr));
        A2h[row][2*kz+1] = hm; A2l[row][2*kz+1] = f2bf(im - bf2f(hm));
    }
    __syncthreads();
    int l = tid & 63, w = tid >> 6, lr = l & 15, kg = l >> 4;
    // ---- phase 2: conv MFMA (split-bf16, 3 terms) -------------------------
    f32x4 dcv[2][4];
    #pragma unroll
    for (int ot = 0; ot < 2; ++ot){
        bf16x8 ah = *(const bf16x8*)&wcvh[layer*1024 + (ot*16 + lr)*32 + kg*8];
        bf16x8 al = *(const bf16x8*)&wcvl[layer*1024 + (ot*16 + lr)*32 + kg*8];
        #pragma unroll
        for (int ptt = 0; ptt < 4; ++ptt){
            bf16x8 bh = *(const bf16x8*)&XT[0][w*64 + ptt*16 + lr][kg*8];
            bf16x8 bl = *(const bf16x8*)&XT[1][w*64 + ptt*16 + lr][kg*8];
            f32x4 d = (f32x4){0.f,0.f,0.f,0.f};
            d = __builtin_amdgcn_mfma_f32_16x16x32_bf16(ah, bh, d, 0, 0, 0);
            d = __builtin_amdgcn_mfma_f32_16x16x32_bf16(ah, bl, d, 0, 0, 0);
            d = __builtin_amdgcn_mfma_f32_16x16x32_bf16(al, bh, d, 0, 0, 0);
            dcv[ot][ptt] = d;
        }
    }
    __syncthreads();   // all XT reads done -> overlay x2s
    float* x2s = (float*)&XT[0][0][0];   // [32][266] fp32
    #pragma unroll
    for (int ot = 0; ot < 2; ++ot)
        #pragma unroll
        for (int ptt = 0; ptt < 4; ++ptt)
            #pragma unroll
            for (int r = 0; r < 4; ++r)
                x2s[(ot*16 + kg*4 + r)*266 + w*64 + ptt*16 + lr] = dcv[ot][ptt][r];
    // ---- phase 3: inverse-t MFMA ------------------------------------------
    f32x4 dt[2][4];
    #pragma unroll
    for (int rt = 0; rt < 2; ++rt){
        bf16x8 ah = *(const bf16x8*)&A2h[w*32 + rt*16 + lr][kg*8];
        bf16x8 al = *(const bf16x8*)&A2l[w*32 + rt*16 + lr][kg*8];
        #pragma unroll
        for (int n = 0; n < 4; ++n){
            bf16x8 bh = *(const bf16x8*)&T2h[(n*16 + lr)*32 + kg*8];
            bf16x8 bl = *(const bf16x8*)&T2l[(n*16 + lr)*32 + kg*8];
            f32x4 d = (f32x4){0.f,0.f,0.f,0.f};
            d = __builtin_amdgcn_mfma_f32_16x16x32_bf16(ah, bh, d, 0, 0, 0);
            d = __builtin_amdgcn_mfma_f32_16x16x32_bf16(ah, bl, d, 0, 0, 0);
            d = __builtin_amdgcn_mfma_f32_16x16x32_bf16(al, bh, d, 0, 0, 0);
            dt[rt][n] = d;
        }
    }
    __syncthreads();   // x2s visible
    // ---- phase 4: epilogue gelu(x1 + x2 + cb) -> xout ---------------------
    size_t outb = (size_t)b*32*SVT + (size_t)s*VT + (size_t)vg*256;
    #pragma unroll
    for (int rt = 0; rt < 2; ++rt){
        int o = 8*w + rt*4 + kg;
        float cbv = cb[layer*32 + o];
        #pragma unroll
        for (int n = 0; n < 4; ++n){
            #pragma unroll
            for (int r = 0; r < 4; ++r){
                int pt = r*64 + n*16 + lr;
                float val = dt[rt][n][r] + x2s[o*266 + pt] + cbv;
                xout[outb + (size_t)o*SVT + pt] = gelu_f(val);
            }
        }
    }
}

// ------- fused skip MLP v6: 128 pts / 512 thr, conflict-free A1 stride -----
template<int LAST>
__global__ __launch_bounds__(512, 8) void k_skip(
    const float* __restrict__ coords,
    const unsigned short* __restrict__ w1dup, const float* __restrict__ pbq,
    const unsigned short* __restrict__ w2bf, const float* __restrict__ s2b,
    const unsigned short* __restrict__ w3bf, const float* __restrict__ s3b,
    int layer, float* __restrict__ xio,
    const float* __restrict__ p1w, const float* __restrict__ p1b,
    const float* __restrict__ p2w, const float* __restrict__ p2b,
    float* __restrict__ out)
{
    __shared__ __align__(16) unsigned short A1[128][132];  // h1/h2 bf16; later overlay
    __shared__ __align__(16) unsigned short zst[8][16][8];

    int tid = threadIdx.x;
    size_t g0 = (size_t)blockIdx.x * 128;
    int b = (int)(g0 >> 18);
    const unsigned short* w2g = w2bf + (size_t)layer * 16384;   // [c][k]
    const unsigned short* w3g = w3bf + (size_t)layer * 4096;    // [c2][k]
    const unsigned short* w1g = w1dup + (size_t)layer * 1024;   // [h][8]
    const float* pbg = pbq + layer*512 + b*128;
    const float* b2g = s2b + layer*128;

    int l  = tid & 63;
    int w  = tid >> 6;        // 0..7
    int lr = l & 15;
    int kg = l >> 4;

    // ---- stage z (hi/lo bf16) for wave's 16 points; wave-local ------------
    if (l < 16){
        size_t g = g0 + (size_t)w*16 + l;
        float z0 = coords[g*3+0], z1 = coords[g*3+1], z2 = coords[g*3+2];
        unsigned short h0 = f2bf(z0), h1 = f2bf(z1), h2 = f2bf(z2);
        bf16x8 pk;
        pk[0] = (short)h0; pk[1] = (short)h1; pk[2] = (short)h2; pk[3] = 0;
        pk[4] = (short)f2bf(z0 - bf2f(h0));
        pk[5] = (short)f2bf(z1 - bf2f(h1));
        pk[6] = (short)f2bf(z2 - bf2f(h2));
        pk[7] = 0;
        *(bf16x8*)&zst[w][l][0] = pk;
    }
    bf16x8 bz;
    if (kg == 0) bz = *(const bf16x8*)&zst[w][lr][0];
    else         bz = (bf16x8){0,0,0,0,0,0,0,0};

    // ---- phase B: h1 = gelu(z@w1 + pb) via MFMA, D[h][p] ------------------
    {
        f32x4 accB[8];
        #pragma unroll
        for (int m = 0; m < 8; ++m) accB[m] = (f32x4){0.f,0.f,0.f,0.f};
        #pragma unroll
        for (int m = 0; m < 8; ++m){
            bf16x8 af = *(const bf16x8*)&w1g[(m*16 + lr)*8];
            accB[m] = __builtin_amdgcn_mfma_f32_16x16x32_bf16(af, bz, accB[m], 0, 0, 0);
        }
        #pragma unroll
        for (int m = 0; m < 8; ++m){
            int c0 = m*16 + kg*4;
            float4 bb = *(const float4*)&pbg[c0];
            us4 pk4;
            pk4[0] = f2bf(gelu_f(accB[m][0] + bb.x));
            pk4[1] = f2bf(gelu_f(accB[m][1] + bb.y));
            pk4[2] = f2bf(gelu_f(accB[m][2] + bb.z));
            pk4[3] = f2bf(gelu_f(accB[m][3] + bb.w));
            *(us4*)&A1[w*16 + lr][c0] = pk4;
        }
    }
    __syncthreads();   // h1 visible to all waves

    // ---- phase C: h2pre = h1 @ w2 (MFMA, swapped -> D[c][p]) --------------
    // wave w owns c-tile w over all 8 p-tiles
    f32x4 accC[8];
    #pragma unroll
    for (int pt = 0; pt < 8; ++pt) accC[pt] = (f32x4){0.f,0.f,0.f,0.f};
    #pragma unroll
    for (int kc = 0; kc < 4; ++kc){
        int ko = kc*32 + kg*8;
        bf16x8 a0 = *(const bf16x8*)&w2g[(w*16 + lr)*128 + ko];
        #pragma unroll
        for (int pt = 0; pt < 8; ++pt){
            bf16x8 bb = lds8(&A1[pt*16 + lr][ko]);
            accC[pt] = __builtin_amdgcn_mfma_f32_16x16x32_bf16(a0, bb, accC[pt], 0, 0, 0);
        }
    }
    __syncthreads();   // all h1 reads done -> safe to overwrite A1 with h2
    {
        int c0 = w*16 + kg*4;
        float4 bb = *(const float4*)&b2g[c0];
        #pragma unroll
        for (int pt = 0; pt < 8; ++pt){
            us4 pk4;
            pk4[0] = f2bf(gelu_f(accC[pt][0] + bb.x));
            pk4[1] = f2bf(gelu_f(accC[pt][1] + bb.y));
            pk4[2] = f2bf(gelu_f(accC[pt][2] + bb.z));
            pk4[3] = f2bf(gelu_f(accC[pt][3] + bb.w));
            *(us4*)&A1[pt*16 + lr][c0] = pk4;
        }
    }
    __syncthreads();   // h2 visible

    // ---- phase D: out = h2 @ w3 (MFMA, unswapped -> D[p][c2]) -------------
    int nD  = w & 1;
    int pt0 = (w >> 1) * 2;
    float b3v = s3b[layer*32 + nD*16 + lr];
    f32x4 c3[2];
    c3[0] = (f32x4){0.f,0.f,0.f,0.f}; c3[1] = (f32x4){0.f,0.f,0.f,0.f};
    #pragma unroll
    for (int kc = 0; kc < 4; ++kc){
        int ko = kc*32 + kg*8;
        bf16x8 bw3 = *(const bf16x8*)&w3g[(nD*16 + lr)*128 + ko];
        bf16x8 aa0 = lds8(&A1[(pt0    )*16 + lr][ko]);
        bf16x8 aa1 = lds8(&A1[(pt0 + 1)*16 + lr][ko]);
        c3[0] = __builtin_amdgcn_mfma_f32_16x16x32_bf16(aa0, bw3, c3[0], 0, 0, 0);
        c3[1] = __builtin_amdgcn_mfma_f32_16x16x32_bf16(aa1, bw3, c3[1], 0, 0, 0);
    }
    __syncthreads();   // all h2 reads done -> A1 free for overlay

    float* outsT = (float*)&A1[0][0];      // [32][132] fp32, transposed
    float* hs    = outsT + 4224;           // [128][17]
    float* p1wS  = outsT + 6400;           // [512]
    float* smB   = outsT + 6912;           // 16 b1 | 16 p2w | 1 p2b
    {
        int c2 = nD*16 + lr;
        #pragma unroll
        for (int q = 0; q < 2; ++q){
            int p0 = (pt0 + q)*16 + kg*4;
            float4 v4;
            v4.x = c3[q][0] + b3v; v4.y = c3[q][1] + b3v;
            v4.z = c3[q][2] + b3v; v4.w = c3[q][3] + b3v;
            *(float4*)&outsT[c2*132 + p0] = v4;
        }
    }
    if (LAST){
        p1wS[tid] = p1w[tid];
        if (tid < 16){ smB[tid] = p1b[tid]; smB[16 + tid] = p2w[tid]; }
        if (tid == 32) smB[32] = p2b[0];
    }
    __syncthreads();

    // ---- rmw: xsum = xio + skip ------------------------------------------
    {
        int c  = tid >> 4;        // 0..31
        int pg = tid & 15;        // 8 floats each
        size_t prel = (g0 & (size_t)(SVT - 1)) + (size_t)pg*8;
        float* gp = xio + (((size_t)(b*32 + c)) << 18) + prel;
        float* op = &outsT[c*132 + pg*8];
        #pragma unroll
        for (int i = 0; i < 8; i += 4){
            float4 xv = *(const float4*)&gp[i];
            float4 ov = *(const float4*)&op[i];
            ov.x += xv.x; ov.y += xv.y; ov.z += xv.z; ov.w += xv.w;
            if (LAST) *(float4*)&op[i] = ov;     // keep xsum in LDS
            else      *(float4*)&gp[i] = ov;     // write back to global
        }
    }
    if (LAST){
        __syncthreads();
        {
            int p  = tid & 127;
            int jq = tid >> 7;    // 0..3 -> 4 j each
            float h[4];
            #pragma unroll
            for (int j = 0; j < 4; ++j) h[j] = smB[jq*4 + j];
            for (int c = 0; c < 32; ++c){
                float xv = outsT[c*132 + p];
                #pragma unroll
                for (int j = 0; j < 4; ++j) h[j] += xv * p1wS[c*16 + jq*4 + j];
            }
            #pragma unroll
            for (int j = 0; j < 4; ++j) hs[p*17 + jq*4 + j] = h[j];
        }
        __syncthreads();
        if (tid < 128){
            float acc = smB[32];
            #pragma unroll
            for (int j = 0; j < 16; ++j) acc += gelu_f(hs[tid*17 + j]) * smB[16 + j];
            out[g0 + tid] = acc;
        }
    }
}

extern "C" void kernel_launch(void* const* d_in, const int* in_sizes, int n_in,
                              void* d_out, int out_size, void* d_ws, size_t ws_size,
                              hipStream_t stream)
{
    (void)in_sizes; (void)n_in; (void)out_size; (void)ws_size;
    const float* coords = (const float*)d_in[0];
    const float* params = (const float*)d_in[1];
    const float* lift_w = (const float*)d_in[2];
    const float* lift_b = (const float*)d_in[3];
    const float* sw1    = (const float*)d_in[4];
    const float* sw2    = (const float*)d_in[5];
    const float* sw3    = (const float*)d_in[6];
    const float* sw4    = (const float*)d_in[7];
    const float* conv_w = (const float*)d_in[8];
    const float* conv_b = (const float*)d_in[9];
    const float* s1w    = (const float*)d_in[10];
    const float* s1b    = (const float*)d_in[11];
    const float* s2w    = (const float*)d_in[12];
    const float* s2b    = (const float*)d_in[13];
    const float* s3w    = (const float*)d_in[14];
    const float* s3b    = (const float*)d_in[15];
    const float* p1w    = (const float*)d_in[16];
    const float* p1b    = (const float*)d_in[17];
    const float* p2w    = (const float*)d_in[18];
    const float* p2b    = (const float*)d_in[19];
    float* out = (float*)d_out;

    char* ws = (char*)d_ws;
    float*  xA = (float*)(ws);                                    // 134,217,728
    float2* X2 = (float2*)(ws + 134217728ull);                    //  18,874,368 (also Z1)
    float2* X3 = (float2*)(ws + 153092096ull);                    //   7,077,888
    float2* Yb = (float2*)(ws + 160169984ull);                    //   7,077,888
    unsigned short* w2bf  = (unsigned short*)(ws + 167247872ull); //     131,072
    unsigned short* w3bf  = (unsigned short*)(ws + 167378944ull); //      32,768
    unsigned short* tdft  = (unsigned short*)(ws + 167411712ull); //       8,192
    unsigned short* T1h   = (unsigned short*)(ws + 167419904ull); //      16,384
    unsigned short* T1l   = (unsigned short*)(ws + 167436288ull); //      16,384
    unsigned short* T2h   = (unsigned short*)(ws + 167452672ull); //       4,096
    unsigned short* T2l   = (unsigned short*)(ws + 167456768ull); //       4,096
    float*          pbq   = (float*)(ws + 167460864ull);          //       8,192
    unsigned short* w1dup = (unsigned short*)(ws + 167469056ull); //       8,192
    unsigned short* wcvh  = (unsigned short*)(ws + 167477248ull); //       8,192
    unsigned short* wcvl  = (unsigned short*)(ws + 167485440ull); //       8,192
    unsigned short* T3h   = (unsigned short*)(ws + 167493632ull); //      12,288
    unsigned short* T3l   = (unsigned short*)(ws + 167505920ull); //      12,288
    // total 167,518,208 B

    k_prep<<<432, 256, 0, stream>>>(params, s1w, s1b, s2w, s3w, conv_w,
                                    w2bf, w3bf, tdft, T1h, T1l, T2h, T2l,
                                    pbq, w1dup, wcvh, wcvl, T3h, T3l);
    k_lift<<<4096, 256, 0, stream>>>(coords, params, lift_w, lift_b, xA);

    for (int l = 0; l < NLAY; ++l){
        k_fwdTV<<<8192, 256, 0, stream>>>(xA, tdft, T3h, T3l, X2);
        k_fwdS<<<1152, 256, 0, stream>>>(X2, X3);
        dim3 gmm(27, 32);
        k_modemix<<<gmm, 256, 0, stream>>>(X3, sw1, sw2, sw3, sw4, l, Yb);
        k_invS<<<1536, 256, 0, stream>>>(Yb, X2);          // Z1 overlays X2
        k_cinvVT<<<4096, 256, 0, stream>>>(xA, X2, T2h, T2l, wcvh, wcvl,
                                           conv_b, l, xA);
        if (l < NLAY - 1)
            k_skip<0><<<8192, 512, 0, stream>>>(coords, w1dup, pbq,
                w2bf, s2b, w3bf, s3b, l, xA, p1w, p1b, p2w, p2b, out);
        else
            k_skip<1><<<8192, 512, 0, stream>>>(coords, w1dup, pbq,
                w2bf, s2b, w3bf, s3b, l, xA, p1w, p1b, p2w, p2b, out);
    }
}